// Round 1
// baseline (4628.192 us; speedup 1.0000x reference)
//
#include <hip/hip_runtime.h>

#define Nn 50000
#define Ee 800000
#define Gg 1000
#define Hh 128
#define Cc 6
#define EPSf 1e-5f

// ---------------- degree / norm precompute ----------------
__global__ void k_init(float* __restrict__ dis, float* __restrict__ cnt) {
    int i = blockIdx.x * blockDim.x + threadIdx.x;
    if (i < Nn) dis[i] = 1.0f;   // deg starts at 1 (self loop)
    if (i < Gg) cnt[i] = 0.0f;
}

__global__ void k_deg(const int* __restrict__ ei, float* __restrict__ dis) {
    int e = blockIdx.x * blockDim.x + threadIdx.x;
    if (e < Ee) atomicAdd(&dis[ei[Ee + e]], 1.0f);   // dst in-degree
}

__global__ void k_deg_fin(float* __restrict__ dis, const int* __restrict__ batch,
                          float* __restrict__ cnt) {
    int i = blockIdx.x * blockDim.x + threadIdx.x;
    if (i < Nn) {
        dis[i] = rsqrtf(dis[i]);
        atomicAdd(&cnt[batch[i]], 1.0f);
    }
}

// ---------------- GEMM: Y[N,H] = X[N,H] @ W[H,H] ----------------
// 32 rows per block, full 128-col width. W staged in LDS (64 KB).
// 256 threads: tc = tid&31 -> 4 contiguous cols (float4); tr = tid>>5 -> 4 rows.
__global__ __launch_bounds__(256) void k_gemm(const float* __restrict__ X,
                                              const float* __restrict__ W,
                                              float* __restrict__ Y) {
    __shared__ float ws[Hh * Hh];
    int tid = threadIdx.x;
    float4* ws4 = (float4*)ws;
    const float4* W4 = (const float4*)W;
#pragma unroll
    for (int i = 0; i < 16; i++) ws4[tid + 256 * i] = W4[tid + 256 * i];
    __syncthreads();

    int tc = tid & 31;
    int tr = tid >> 5;
    int row0 = blockIdx.x * 32 + tr * 4;

    int r[4];
#pragma unroll
    for (int i = 0; i < 4; i++) {
        int rr = row0 + i;
        r[i] = rr < Nn ? rr : (Nn - 1);   // clamp; store is guarded
    }

    float acc[4][4] = {};
    for (int k4 = 0; k4 < Hh / 4; k4++) {
        float4 xv[4];
#pragma unroll
        for (int i = 0; i < 4; i++)
            xv[i] = ((const float4*)(X + r[i] * Hh))[k4];
#pragma unroll
        for (int kk = 0; kk < 4; kk++) {
            float4 wv = ((const float4*)(ws + (k4 * 4 + kk) * Hh))[tc];
#pragma unroll
            for (int i = 0; i < 4; i++) {
                float xs = (&xv[i].x)[kk];
                acc[i][0] += xs * wv.x;
                acc[i][1] += xs * wv.y;
                acc[i][2] += xs * wv.z;
                acc[i][3] += xs * wv.w;
            }
        }
    }
#pragma unroll
    for (int i = 0; i < 4; i++) {
        int rr = row0 + i;
        if (rr < Nn)
            ((float4*)(Y + rr * Hh))[tc] =
                make_float4(acc[i][0], acc[i][1], acc[i][2], acc[i][3]);
    }
}

// ---------------- A = H*self_norm + bias (self-loop term) ----------------
__global__ void k_preagg(const float* __restrict__ Hb, const float* __restrict__ dis,
                         const float* __restrict__ bias, float* __restrict__ A) {
    int tid = blockIdx.x * blockDim.x + threadIdx.x;
    if (tid >= Nn * 32) return;
    int i = tid >> 5, c4 = tid & 31;
    float d = dis[i];
    float sn = d * d;
    float4 v = ((const float4*)Hb)[tid];
    float4 b = ((const float4*)bias)[c4];
    float4 o;
    o.x = v.x * sn + b.x;
    o.y = v.y * sn + b.y;
    o.z = v.z * sn + b.z;
    o.w = v.w * sn + b.w;
    ((float4*)A)[tid] = o;
}

// ---------------- edge scatter: A[dst] += H[src] * norm ----------------
__global__ void k_scatter(const int* __restrict__ ei, const float* __restrict__ Hb,
                          const float* __restrict__ dis, float* __restrict__ A) {
    int idx = blockIdx.x * blockDim.x + threadIdx.x;
    if (idx >= Ee * 32) return;
    int e = idx >> 5, c4 = idx & 31;
    int s = ei[e];
    int d = ei[Ee + e];
    float nrm = dis[s] * dis[d];
    float4 v = ((const float4*)Hb)[s * 32 + c4];
    float* p = A + d * Hh + c4 * 4;
    atomicAdd(p + 0, v.x * nrm);
    atomicAdd(p + 1, v.y * nrm);
    atomicAdd(p + 2, v.z * nrm);
    atomicAdd(p + 3, v.w * nrm);
}

// ---------------- BN stats: per-channel sum & sumsq ----------------
__global__ __launch_bounds__(256) void k_stats(const float* __restrict__ A,
                                               float* __restrict__ stats) {
    __shared__ float s1[256], s2[256];
    int tid = threadIdx.x;
    int c = tid & 127;
    int half = tid >> 7;
    float sum = 0.f, sq = 0.f;
    for (int r = blockIdx.x * 2 + half; r < Nn; r += gridDim.x * 2) {
        float v = A[r * Hh + c];
        sum += v;
        sq += v * v;
    }
    s1[tid] = sum;
    s2[tid] = sq;
    __syncthreads();
    if (half == 0) {
        atomicAdd(&stats[c], s1[c] + s1[c + 128]);
        atomicAdd(&stats[Hh + c], s2[c] + s2[c + 128]);
    }
}

// ---------------- BN normalize + affine + relu (in place ok) ----------------
__global__ void k_norm(const float* __restrict__ A, const float* __restrict__ stats,
                       const float* __restrict__ gam, const float* __restrict__ bet,
                       float* __restrict__ Xo) {
    int tid = blockIdx.x * blockDim.x + threadIdx.x;
    if (tid >= Nn * 32) return;
    int c4 = tid & 31;
    float4 v = ((const float4*)A)[tid];
    float4 o;
#pragma unroll
    for (int j = 0; j < 4; j++) {
        int c = c4 * 4 + j;
        float mu = stats[c] * (1.0f / Nn);
        float var = stats[Hh + c] * (1.0f / Nn) - mu * mu;
        float istd = rsqrtf(var + EPSf);
        float val = ((&v.x)[j] - mu) * istd * gam[c] + bet[c];
        (&o.x)[j] = fmaxf(val, 0.0f);
    }
    ((float4*)Xo)[tid] = o;
}

// ---------------- global mean pool (scatter part) ----------------
__global__ void k_pool(const float* __restrict__ X, const int* __restrict__ batch,
                       float* __restrict__ pooled) {
    int tid = blockIdx.x * blockDim.x + threadIdx.x;
    if (tid >= Nn * 32) return;
    int i = tid >> 5, c4 = tid & 31;
    int g = batch[i];
    float4 v = ((const float4*)X)[tid];
    float* p = pooled + g * Hh + c4 * 4;
    atomicAdd(p + 0, v.x);
    atomicAdd(p + 1, v.y);
    atomicAdd(p + 2, v.z);
    atomicAdd(p + 3, v.w);
}

// ---------------- MLP head: relu(pooled/cnt @ W1 + b1) @ W2 + b2 ----------------
__global__ __launch_bounds__(128) void k_mlp(const float* __restrict__ pooled,
                                             const float* __restrict__ cnt,
                                             const float* __restrict__ W1,
                                             const float* __restrict__ b1,
                                             const float* __restrict__ W2,
                                             const float* __restrict__ b2,
                                             float* __restrict__ out) {
    int g = blockIdx.x;
    int c = threadIdx.x;
    __shared__ float p[Hh];
    __shared__ float hid[Hh];
    float inv = 1.0f / fmaxf(cnt[g], 1.0f);
    p[c] = pooled[g * Hh + c] * inv;
    __syncthreads();
    float acc = b1[c];
    for (int k = 0; k < Hh; k++) acc += p[k] * W1[k * Hh + c];
    hid[c] = fmaxf(acc, 0.0f);
    __syncthreads();
    if (c < Cc) {
        float acc2 = b2[c];
        for (int k = 0; k < Hh; k++) acc2 += hid[k] * W2[k * Cc + c];
        out[g * Cc + c] = acc2;
    }
}

extern "C" void kernel_launch(void* const* d_in, const int* in_sizes, int n_in,
                              void* d_out, int out_size, void* d_ws, size_t ws_size,
                              hipStream_t stream) {
    const float* x      = (const float*)d_in[0];
    const int*   ei     = (const int*)d_in[1];
    const int*   batch  = (const int*)d_in[2];
    const float* conv_w = (const float*)d_in[3];
    const float* conv_b = (const float*)d_in[4];
    const float* bn_g   = (const float*)d_in[5];
    const float* bn_b   = (const float*)d_in[6];
    const float* w1     = (const float*)d_in[7];
    const float* b1     = (const float*)d_in[8];
    const float* w2     = (const float*)d_in[9];
    const float* b2     = (const float*)d_in[10];
    float* out = (float*)d_out;

    float* B0     = (float*)d_ws;            // N*H  (GEMM out / gather src)
    float* B1     = B0 + Nn * Hh;            // N*H  (agg / normalized x)
    float* dis    = B1 + Nn * Hh;            // N
    float* cnt    = dis + Nn;                // G
    float* stats  = cnt + Gg;                // 2*H
    float* pooled = stats + 2 * Hh;          // G*H

    k_init<<<(Nn + 255) / 256, 256, 0, stream>>>(dis, cnt);
    k_deg<<<(Ee + 255) / 256, 256, 0, stream>>>(ei, dis);
    k_deg_fin<<<(Nn + 255) / 256, 256, 0, stream>>>(dis, batch, cnt);

    const float* cur = x;
    for (int l = 0; l < 3; l++) {
        k_gemm<<<(Nn + 31) / 32, 256, 0, stream>>>(cur, conv_w + l * Hh * Hh, B0);
        k_preagg<<<(Nn * 32 + 255) / 256, 256, 0, stream>>>(B0, dis, conv_b + l * Hh, B1);
        k_scatter<<<(Ee * 32 + 255) / 256, 256, 0, stream>>>(ei, B0, dis, B1);
        hipMemsetAsync(stats, 0, 2 * Hh * sizeof(float), stream);
        k_stats<<<256, 256, 0, stream>>>(B1, stats);
        k_norm<<<(Nn * 32 + 255) / 256, 256, 0, stream>>>(B1, stats, bn_g + l * Hh,
                                                          bn_b + l * Hh, B1);
        cur = B1;
    }

    hipMemsetAsync(pooled, 0, Gg * Hh * sizeof(float), stream);
    k_pool<<<(Nn * 32 + 255) / 256, 256, 0, stream>>>(B1, batch, pooled);
    k_mlp<<<Gg, 128, 0, stream>>>(pooled, cnt, w1, b1, w2, b2, out);
}

// Round 2
// 888.845 us; speedup vs baseline: 5.2070x; 5.2070x over previous
//
#include <hip/hip_runtime.h>

#define Nn 50000
#define Ee 800000
#define Gg 1000
#define Hh 128
#define Cc 6
#define EPSf 1e-5f
#define SCAN_T 1024

// ---------------- init: zero indeg + cnt ----------------
__global__ void k_init(int* __restrict__ indeg, float* __restrict__ cnt) {
    int i = blockIdx.x * blockDim.x + threadIdx.x;
    if (i < Nn) indeg[i] = 0;
    if (i < Gg) cnt[i] = 0.0f;
}

// ---------------- in-degree histogram ----------------
__global__ void k_deg(const int* __restrict__ ei, int* __restrict__ indeg) {
    int e = blockIdx.x * blockDim.x + threadIdx.x;
    if (e < Ee) atomicAdd(&indeg[ei[Ee + e]], 1);
}

__global__ void k_deg_fin(const int* __restrict__ indeg, float* __restrict__ dis,
                          const int* __restrict__ batch, float* __restrict__ cnt) {
    int i = blockIdx.x * blockDim.x + threadIdx.x;
    if (i < Nn) {
        dis[i] = rsqrtf((float)indeg[i] + 1.0f);
        atomicAdd(&cnt[batch[i]], 1.0f);
    }
}

// ---------------- single-block exclusive scan over indeg -> rs (segment starts) ----------------
__global__ __launch_bounds__(SCAN_T) void k_scan(const int* __restrict__ indeg,
                                                 int* __restrict__ rs) {
    __shared__ int part[SCAN_T];
    int t = threadIdx.x;
    const int CH = (Nn + SCAN_T - 1) / SCAN_T;   // 49
    int beg = t * CH;
    int end = beg + CH < Nn ? beg + CH : Nn;
    int s = 0;
    for (int i = beg; i < end; i++) s += indeg[i];
    part[t] = s;
    __syncthreads();
    for (int off = 1; off < SCAN_T; off <<= 1) {
        int v = (t >= off) ? part[t - off] : 0;
        __syncthreads();
        part[t] += v;
        __syncthreads();
    }
    int excl = (t == 0) ? 0 : part[t - 1];
    for (int i = beg; i < end; i++) {
        rs[i] = excl;
        excl += indeg[i];
    }
}

// ---------------- counting-sort fill: csr_src grouped by dst ----------------
// After this kernel rs[d] == end of segment d (== original rs[d+1]).
__global__ void k_fill(const int* __restrict__ ei, int* __restrict__ rs,
                       int* __restrict__ csr_src) {
    int e = blockIdx.x * blockDim.x + threadIdx.x;
    if (e >= Ee) return;
    int s = ei[e];
    int d = ei[Ee + e];
    int slot = atomicAdd(&rs[d], 1);
    csr_src[slot] = s;
}

// ---------------- GEMM: Y[N,H] = X[N,H] @ W[H,H] ----------------
__global__ __launch_bounds__(256) void k_gemm(const float* __restrict__ X,
                                              const float* __restrict__ W,
                                              float* __restrict__ Y) {
    __shared__ float ws[Hh * Hh];
    int tid = threadIdx.x;
    float4* ws4 = (float4*)ws;
    const float4* W4 = (const float4*)W;
#pragma unroll
    for (int i = 0; i < 16; i++) ws4[tid + 256 * i] = W4[tid + 256 * i];
    __syncthreads();

    int tc = tid & 31;
    int tr = tid >> 5;
    int row0 = blockIdx.x * 32 + tr * 4;

    int r[4];
#pragma unroll
    for (int i = 0; i < 4; i++) {
        int rr = row0 + i;
        r[i] = rr < Nn ? rr : (Nn - 1);
    }

    float acc[4][4] = {};
    for (int k4 = 0; k4 < Hh / 4; k4++) {
        float4 xv[4];
#pragma unroll
        for (int i = 0; i < 4; i++)
            xv[i] = ((const float4*)(X + r[i] * Hh))[k4];
#pragma unroll
        for (int kk = 0; kk < 4; kk++) {
            float4 wv = ((const float4*)(ws + (k4 * 4 + kk) * Hh))[tc];
#pragma unroll
            for (int i = 0; i < 4; i++) {
                float xs = (&xv[i].x)[kk];
                acc[i][0] += xs * wv.x;
                acc[i][1] += xs * wv.y;
                acc[i][2] += xs * wv.z;
                acc[i][3] += xs * wv.w;
            }
        }
    }
#pragma unroll
    for (int i = 0; i < 4; i++) {
        int rr = row0 + i;
        if (rr < Nn)
            ((float4*)(Y + rr * Hh))[tc] =
                make_float4(acc[i][0], acc[i][1], acc[i][2], acc[i][3]);
    }
}

// ---------------- CSR gather: A[n] = sum_{e in in(n)} H[src]*norm + H[n]/deg + bias ----------------
// One wave (64 lanes) per node; lane covers 2 channels (float2).
__global__ __launch_bounds__(256) void k_gather(const float* __restrict__ Hb,
                                                const float* __restrict__ dis,
                                                const float* __restrict__ bias,
                                                const int* __restrict__ rs,
                                                const int* __restrict__ csr_src,
                                                float* __restrict__ A) {
    int node = blockIdx.x * 4 + (threadIdx.x >> 6);
    if (node >= Nn) return;
    int lane = threadIdx.x & 63;

    float dn = dis[node];
    float2 hs = ((const float2*)(Hb + node * Hh))[lane];
    float2 bv = ((const float2*)bias)[lane];
    float sn = dn * dn;
    float2 acc;
    acc.x = hs.x * sn + bv.x;
    acc.y = hs.y * sn + bv.y;

    int beg = (node == 0) ? 0 : rs[node - 1];   // rs[d] = segment end after fill
    int end = rs[node];

    int j = beg;
    for (; j + 1 < end; j += 2) {
        int s0 = csr_src[j];
        int s1 = csr_src[j + 1];
        float n0 = dis[s0] * dn;
        float n1 = dis[s1] * dn;
        float2 v0 = ((const float2*)(Hb + s0 * Hh))[lane];
        float2 v1 = ((const float2*)(Hb + s1 * Hh))[lane];
        acc.x += v0.x * n0 + v1.x * n1;
        acc.y += v0.y * n0 + v1.y * n1;
    }
    if (j < end) {
        int s0 = csr_src[j];
        float n0 = dis[s0] * dn;
        float2 v0 = ((const float2*)(Hb + s0 * Hh))[lane];
        acc.x += v0.x * n0;
        acc.y += v0.y * n0;
    }
    ((float2*)(A + node * Hh))[lane] = acc;
}

// ---------------- BN stats: per-channel sum & sumsq ----------------
__global__ __launch_bounds__(256) void k_stats(const float* __restrict__ A,
                                               float* __restrict__ stats) {
    __shared__ float s1[256], s2[256];
    int tid = threadIdx.x;
    int c = tid & 127;
    int half = tid >> 7;
    float sum = 0.f, sq = 0.f;
    for (int r = blockIdx.x * 2 + half; r < Nn; r += gridDim.x * 2) {
        float v = A[r * Hh + c];
        sum += v;
        sq += v * v;
    }
    s1[tid] = sum;
    s2[tid] = sq;
    __syncthreads();
    if (half == 0) {
        atomicAdd(&stats[c], s1[c] + s1[c + 128]);
        atomicAdd(&stats[Hh + c], s2[c] + s2[c + 128]);
    }
}

// ---------------- BN normalize + affine + relu ----------------
__global__ void k_norm(const float* __restrict__ A, const float* __restrict__ stats,
                       const float* __restrict__ gam, const float* __restrict__ bet,
                       float* __restrict__ Xo) {
    int tid = blockIdx.x * blockDim.x + threadIdx.x;
    if (tid >= Nn * 32) return;
    int c4 = tid & 31;
    float4 v = ((const float4*)A)[tid];
    float4 o;
#pragma unroll
    for (int j = 0; j < 4; j++) {
        int c = c4 * 4 + j;
        float mu = stats[c] * (1.0f / Nn);
        float var = stats[Hh + c] * (1.0f / Nn) - mu * mu;
        float istd = rsqrtf(var + EPSf);
        float val = ((&v.x)[j] - mu) * istd * gam[c] + bet[c];
        (&o.x)[j] = fmaxf(val, 0.0f);
    }
    ((float4*)Xo)[tid] = o;
}

// ---------------- global mean pool (scatter part) ----------------
__global__ void k_pool(const float* __restrict__ X, const int* __restrict__ batch,
                       float* __restrict__ pooled) {
    int tid = blockIdx.x * blockDim.x + threadIdx.x;
    if (tid >= Nn * 32) return;
    int i = tid >> 5, c4 = tid & 31;
    int g = batch[i];
    float4 v = ((const float4*)X)[tid];
    float* p = pooled + g * Hh + c4 * 4;
    atomicAdd(p + 0, v.x);
    atomicAdd(p + 1, v.y);
    atomicAdd(p + 2, v.z);
    atomicAdd(p + 3, v.w);
}

// ---------------- MLP head ----------------
__global__ __launch_bounds__(128) void k_mlp(const float* __restrict__ pooled,
                                             const float* __restrict__ cnt,
                                             const float* __restrict__ W1,
                                             const float* __restrict__ b1,
                                             const float* __restrict__ W2,
                                             const float* __restrict__ b2,
                                             float* __restrict__ out) {
    int g = blockIdx.x;
    int c = threadIdx.x;
    __shared__ float p[Hh];
    __shared__ float hid[Hh];
    float inv = 1.0f / fmaxf(cnt[g], 1.0f);
    p[c] = pooled[g * Hh + c] * inv;
    __syncthreads();
    float acc = b1[c];
    for (int k = 0; k < Hh; k++) acc += p[k] * W1[k * Hh + c];
    hid[c] = fmaxf(acc, 0.0f);
    __syncthreads();
    if (c < Cc) {
        float acc2 = b2[c];
        for (int k = 0; k < Hh; k++) acc2 += hid[k] * W2[k * Cc + c];
        out[g * Cc + c] = acc2;
    }
}

extern "C" void kernel_launch(void* const* d_in, const int* in_sizes, int n_in,
                              void* d_out, int out_size, void* d_ws, size_t ws_size,
                              hipStream_t stream) {
    const float* x      = (const float*)d_in[0];
    const int*   ei     = (const int*)d_in[1];
    const int*   batch  = (const int*)d_in[2];
    const float* conv_w = (const float*)d_in[3];
    const float* conv_b = (const float*)d_in[4];
    const float* bn_g   = (const float*)d_in[5];
    const float* bn_b   = (const float*)d_in[6];
    const float* w1     = (const float*)d_in[7];
    const float* b1     = (const float*)d_in[8];
    const float* w2     = (const float*)d_in[9];
    const float* b2     = (const float*)d_in[10];
    float* out = (float*)d_out;

    float* B0      = (float*)d_ws;           // N*H
    float* B1      = B0 + Nn * Hh;           // N*H
    float* dis     = B1 + Nn * Hh;           // N
    float* cnt     = dis + Nn;               // G
    float* stats   = cnt + Gg;               // 2*H
    float* pooled  = stats + 2 * Hh;         // G*H
    int*   indeg   = (int*)(pooled + Gg * Hh);  // N
    int*   rs      = indeg + Nn;             // N
    int*   csr_src = rs + Nn;                // E

    // ---- CSR build (per launch; ws is re-poisoned every call) ----
    k_init<<<(Nn + 255) / 256, 256, 0, stream>>>(indeg, cnt);
    k_deg<<<(Ee + 255) / 256, 256, 0, stream>>>(ei, indeg);
    k_deg_fin<<<(Nn + 255) / 256, 256, 0, stream>>>(indeg, dis, batch, cnt);
    k_scan<<<1, SCAN_T, 0, stream>>>(indeg, rs);
    k_fill<<<(Ee + 255) / 256, 256, 0, stream>>>(ei, rs, csr_src);

    const float* cur = x;
    for (int l = 0; l < 3; l++) {
        k_gemm<<<(Nn + 31) / 32, 256, 0, stream>>>(cur, conv_w + l * Hh * Hh, B0);
        k_gather<<<(Nn + 3) / 4, 256, 0, stream>>>(B0, dis, conv_b + l * Hh, rs,
                                                   csr_src, B1);
        hipMemsetAsync(stats, 0, 2 * Hh * sizeof(float), stream);
        k_stats<<<256, 256, 0, stream>>>(B1, stats);
        k_norm<<<(Nn * 32 + 255) / 256, 256, 0, stream>>>(B1, stats, bn_g + l * Hh,
                                                          bn_b + l * Hh, B1);
        cur = B1;
    }

    hipMemsetAsync(pooled, 0, Gg * Hh * sizeof(float), stream);
    k_pool<<<(Nn * 32 + 255) / 256, 256, 0, stream>>>(B1, batch, pooled);
    k_mlp<<<Gg, 128, 0, stream>>>(pooled, cnt, w1, b1, w2, b2, out);
}

// Round 3
// 713.034 us; speedup vs baseline: 6.4908x; 1.2466x over previous
//
#include <hip/hip_runtime.h>

#define Nn 50000
#define Ee 800000
#define Gg 1000
#define Hh 128
#define Cc 6
#define EPSf 1e-5f
#define SCAN_T 1024

// ---------------- init: zero indeg ----------------
__global__ void k_init(int* __restrict__ indeg) {
    int i = blockIdx.x * blockDim.x + threadIdx.x;
    if (i < Nn) indeg[i] = 0;
}

// ---------------- in-degree histogram ----------------
__global__ void k_deg(const int* __restrict__ ei, int* __restrict__ indeg) {
    int e = blockIdx.x * blockDim.x + threadIdx.x;
    if (e < Ee) atomicAdd(&indeg[ei[Ee + e]], 1);
}

__global__ void k_deg_fin(const int* __restrict__ indeg, float* __restrict__ dis) {
    int i = blockIdx.x * blockDim.x + threadIdx.x;
    if (i < Nn) dis[i] = rsqrtf((float)indeg[i] + 1.0f);
}

// ---------------- graph start offsets via binary search on sorted batch ----------------
__global__ void k_gbounds(const int* __restrict__ batch, int* __restrict__ gstart) {
    int g = blockIdx.x * blockDim.x + threadIdx.x;
    if (g > Gg) return;
    int lo = 0, hi = Nn;
    while (lo < hi) {
        int mid = (lo + hi) >> 1;
        if (batch[mid] < g) lo = mid + 1; else hi = mid;
    }
    gstart[g] = lo;
}

// ---------------- single-block exclusive scan over indeg -> rs ----------------
__global__ __launch_bounds__(SCAN_T) void k_scan(const int* __restrict__ indeg,
                                                 int* __restrict__ rs) {
    __shared__ int part[SCAN_T];
    int t = threadIdx.x;
    const int CH = (Nn + SCAN_T - 1) / SCAN_T;   // 49
    int beg = t * CH;
    int end = beg + CH < Nn ? beg + CH : Nn;
    int s = 0;
    for (int i = beg; i < end; i++) s += indeg[i];
    part[t] = s;
    __syncthreads();
    for (int off = 1; off < SCAN_T; off <<= 1) {
        int v = (t >= off) ? part[t - off] : 0;
        __syncthreads();
        part[t] += v;
        __syncthreads();
    }
    int excl = (t == 0) ? 0 : part[t - 1];
    for (int i = beg; i < end; i++) {
        rs[i] = excl;
        excl += indeg[i];
    }
}

// ---------------- counting-sort fill: csr_src grouped by dst ----------------
// After this kernel rs[d] == end of segment d.
__global__ void k_fill(const int* __restrict__ ei, int* __restrict__ rs,
                       int* __restrict__ csr_src) {
    int e = blockIdx.x * blockDim.x + threadIdx.x;
    if (e >= Ee) return;
    int s = ei[e];
    int d = ei[Ee + e];
    int slot = atomicAdd(&rs[d], 1);
    csr_src[slot] = s;
}

// ---------------- GEMM: Y[N,H] = X[N,H] @ W[H,H] ----------------
__global__ __launch_bounds__(256) void k_gemm(const float* __restrict__ X,
                                              const float* __restrict__ W,
                                              float* __restrict__ Y) {
    __shared__ float ws[Hh * Hh];
    int tid = threadIdx.x;
    float4* ws4 = (float4*)ws;
    const float4* W4 = (const float4*)W;
#pragma unroll
    for (int i = 0; i < 16; i++) ws4[tid + 256 * i] = W4[tid + 256 * i];
    __syncthreads();

    int tc = tid & 31;
    int tr = tid >> 5;
    int row0 = blockIdx.x * 32 + tr * 4;

    int r[4];
#pragma unroll
    for (int i = 0; i < 4; i++) {
        int rr = row0 + i;
        r[i] = rr < Nn ? rr : (Nn - 1);
    }

    float acc[4][4] = {};
    for (int k4 = 0; k4 < Hh / 4; k4++) {
        float4 xv[4];
#pragma unroll
        for (int i = 0; i < 4; i++)
            xv[i] = ((const float4*)(X + r[i] * Hh))[k4];
#pragma unroll
        for (int kk = 0; kk < 4; kk++) {
            float4 wv = ((const float4*)(ws + (k4 * 4 + kk) * Hh))[tc];
#pragma unroll
            for (int i = 0; i < 4; i++) {
                float xs = (&xv[i].x)[kk];
                acc[i][0] += xs * wv.x;
                acc[i][1] += xs * wv.y;
                acc[i][2] += xs * wv.z;
                acc[i][3] += xs * wv.w;
            }
        }
    }
#pragma unroll
    for (int i = 0; i < 4; i++) {
        int rr = row0 + i;
        if (rr < Nn)
            ((float4*)(Y + rr * Hh))[tc] =
                make_float4(acc[i][0], acc[i][1], acc[i][2], acc[i][3]);
    }
}

// ---------------- CSR gather ----------------
__global__ __launch_bounds__(256) void k_gather(const float* __restrict__ Hb,
                                                const float* __restrict__ dis,
                                                const float* __restrict__ bias,
                                                const int* __restrict__ rs,
                                                const int* __restrict__ csr_src,
                                                float* __restrict__ A) {
    int node = blockIdx.x * 4 + (threadIdx.x >> 6);
    if (node >= Nn) return;
    int lane = threadIdx.x & 63;

    float dn = dis[node];
    float2 hs = ((const float2*)(Hb + node * Hh))[lane];
    float2 bv = ((const float2*)bias)[lane];
    float sn = dn * dn;
    float2 acc;
    acc.x = hs.x * sn + bv.x;
    acc.y = hs.y * sn + bv.y;

    int beg = (node == 0) ? 0 : rs[node - 1];
    int end = rs[node];

    int j = beg;
    for (; j + 1 < end; j += 2) {
        int s0 = csr_src[j];
        int s1 = csr_src[j + 1];
        float n0 = dis[s0] * dn;
        float n1 = dis[s1] * dn;
        float2 v0 = ((const float2*)(Hb + s0 * Hh))[lane];
        float2 v1 = ((const float2*)(Hb + s1 * Hh))[lane];
        acc.x += v0.x * n0 + v1.x * n1;
        acc.y += v0.y * n0 + v1.y * n1;
    }
    if (j < end) {
        int s0 = csr_src[j];
        float n0 = dis[s0] * dn;
        float2 v0 = ((const float2*)(Hb + s0 * Hh))[lane];
        acc.x += v0.x * n0;
        acc.y += v0.y * n0;
    }
    ((float2*)(A + node * Hh))[lane] = acc;
}

// ---------------- BN stats: per-channel sum & sumsq ----------------
__global__ __launch_bounds__(256) void k_stats(const float* __restrict__ A,
                                               float* __restrict__ stats) {
    __shared__ float s1[256], s2[256];
    int tid = threadIdx.x;
    int c = tid & 127;
    int half = tid >> 7;
    float sum = 0.f, sq = 0.f;
    for (int r = blockIdx.x * 2 + half; r < Nn; r += gridDim.x * 2) {
        float v = A[r * Hh + c];
        sum += v;
        sq += v * v;
    }
    s1[tid] = sum;
    s2[tid] = sq;
    __syncthreads();
    if (half == 0) {
        atomicAdd(&stats[c], s1[c] + s1[c + 128]);
        atomicAdd(&stats[Hh + c], s2[c] + s2[c + 128]);
    }
}

// ---------------- BN normalize + affine + relu ----------------
__global__ void k_norm(const float* __restrict__ A, const float* __restrict__ stats,
                       const float* __restrict__ gam, const float* __restrict__ bet,
                       float* __restrict__ Xo) {
    int tid = blockIdx.x * blockDim.x + threadIdx.x;
    if (tid >= Nn * 32) return;
    int c4 = tid & 31;
    float4 v = ((const float4*)A)[tid];
    float4 o;
#pragma unroll
    for (int j = 0; j < 4; j++) {
        int c = c4 * 4 + j;
        float mu = stats[c] * (1.0f / Nn);
        float var = stats[Hh + c] * (1.0f / Nn) - mu * mu;
        float istd = rsqrtf(var + EPSf);
        float val = ((&v.x)[j] - mu) * istd * gam[c] + bet[c];
        (&o.x)[j] = fmaxf(val, 0.0f);
    }
    ((float4*)Xo)[tid] = o;
}

// ---------------- segmented mean pool: one block per graph, no atomics ----------------
__global__ __launch_bounds__(128) void k_pool_seg(const float* __restrict__ X,
                                                  const int* __restrict__ gstart,
                                                  float* __restrict__ pooled) {
    int g = blockIdx.x;
    int c = threadIdx.x;
    int s = gstart[g], e = gstart[g + 1];
    float sum = 0.0f;
    for (int r = s; r < e; r++) sum += X[r * Hh + c];
    pooled[g * Hh + c] = sum;
}

// ---------------- MLP head ----------------
__global__ __launch_bounds__(128) void k_mlp(const float* __restrict__ pooled,
                                             const int* __restrict__ gstart,
                                             const float* __restrict__ W1,
                                             const float* __restrict__ b1,
                                             const float* __restrict__ W2,
                                             const float* __restrict__ b2,
                                             float* __restrict__ out) {
    int g = blockIdx.x;
    int c = threadIdx.x;
    __shared__ float p[Hh];
    __shared__ float hid[Hh];
    int n = gstart[g + 1] - gstart[g];
    float inv = 1.0f / (float)(n > 1 ? n : 1);
    p[c] = pooled[g * Hh + c] * inv;
    __syncthreads();
    float acc = b1[c];
    for (int k = 0; k < Hh; k++) acc += p[k] * W1[k * Hh + c];
    hid[c] = fmaxf(acc, 0.0f);
    __syncthreads();
    if (c < Cc) {
        float acc2 = b2[c];
        for (int k = 0; k < Hh; k++) acc2 += hid[k] * W2[k * Cc + c];
        out[g * Cc + c] = acc2;
    }
}

extern "C" void kernel_launch(void* const* d_in, const int* in_sizes, int n_in,
                              void* d_out, int out_size, void* d_ws, size_t ws_size,
                              hipStream_t stream) {
    const float* x      = (const float*)d_in[0];
    const int*   ei     = (const int*)d_in[1];
    const int*   batch  = (const int*)d_in[2];
    const float* conv_w = (const float*)d_in[3];
    const float* conv_b = (const float*)d_in[4];
    const float* bn_g   = (const float*)d_in[5];
    const float* bn_b   = (const float*)d_in[6];
    const float* w1     = (const float*)d_in[7];
    const float* b1     = (const float*)d_in[8];
    const float* w2     = (const float*)d_in[9];
    const float* b2     = (const float*)d_in[10];
    float* out = (float*)d_out;

    float* B0      = (float*)d_ws;              // N*H
    float* B1      = B0 + Nn * Hh;              // N*H
    float* dis     = B1 + Nn * Hh;              // N
    float* stats   = dis + Nn;                  // 2*H
    float* pooled  = stats + 2 * Hh;            // G*H
    int*   indeg   = (int*)(pooled + Gg * Hh);  // N
    int*   rs      = indeg + Nn;                // N
    int*   gstart  = rs + Nn;                   // G+1
    int*   csr_src = gstart + Gg + 1;           // E

    // ---- CSR build + graph bounds (per launch; ws re-poisoned every call) ----
    k_init<<<(Nn + 255) / 256, 256, 0, stream>>>(indeg);
    k_deg<<<(Ee + 255) / 256, 256, 0, stream>>>(ei, indeg);
    k_deg_fin<<<(Nn + 255) / 256, 256, 0, stream>>>(indeg, dis);
    k_gbounds<<<(Gg + 256) / 256, 256, 0, stream>>>(batch, gstart);
    k_scan<<<1, SCAN_T, 0, stream>>>(indeg, rs);
    k_fill<<<(Ee + 255) / 256, 256, 0, stream>>>(ei, rs, csr_src);

    const float* cur = x;
    for (int l = 0; l < 3; l++) {
        k_gemm<<<(Nn + 31) / 32, 256, 0, stream>>>(cur, conv_w + l * Hh * Hh, B0);
        k_gather<<<(Nn + 3) / 4, 256, 0, stream>>>(B0, dis, conv_b + l * Hh, rs,
                                                   csr_src, B1);
        hipMemsetAsync(stats, 0, 2 * Hh * sizeof(float), stream);
        k_stats<<<256, 256, 0, stream>>>(B1, stats);
        k_norm<<<(Nn * 32 + 255) / 256, 256, 0, stream>>>(B1, stats, bn_g + l * Hh,
                                                          bn_b + l * Hh, B1);
        cur = B1;
    }

    k_pool_seg<<<Gg, 128, 0, stream>>>(B1, gstart, pooled);
    k_mlp<<<Gg, 128, 0, stream>>>(pooled, gstart, w1, b1, w2, b2, out);
}

// Round 4
// 647.272 us; speedup vs baseline: 7.1503x; 1.1016x over previous
//
#include <hip/hip_runtime.h>

#define Nn 50000
#define Ee 800000
#define Gg 1000
#define Hh 128
#define Cc 6
#define EPSf 1e-5f
#define SB 1024                       // elements per scan block
#define NSB ((Nn + SB - 1) / SB)      // 49

// ---------------- init: zero indeg ----------------
__global__ void k_init(int* __restrict__ indeg) {
    int i = blockIdx.x * blockDim.x + threadIdx.x;
    if (i < Nn) indeg[i] = 0;
}

// ---------------- in-degree histogram ----------------
__global__ void k_deg(const int* __restrict__ ei, int* __restrict__ indeg) {
    int e = blockIdx.x * blockDim.x + threadIdx.x;
    if (e < Ee) atomicAdd(&indeg[ei[Ee + e]], 1);
}

__global__ void k_deg_fin(const int* __restrict__ indeg, float* __restrict__ dis) {
    int i = blockIdx.x * blockDim.x + threadIdx.x;
    if (i < Nn) dis[i] = rsqrtf((float)indeg[i] + 1.0f);
}

// ---------------- graph start offsets via binary search on sorted batch ----------------
__global__ void k_gbounds(const int* __restrict__ batch, int* __restrict__ gstart) {
    int g = blockIdx.x * blockDim.x + threadIdx.x;
    if (g > Gg) return;
    int lo = 0, hi = Nn;
    while (lo < hi) {
        int mid = (lo + hi) >> 1;
        if (batch[mid] < g) lo = mid + 1; else hi = mid;
    }
    gstart[g] = lo;
}

// ---------------- multi-block exclusive scan: phase 1 ----------------
// Block-local exclusive scan of indeg into rs; block total into bsum.
__global__ __launch_bounds__(256) void k_scan_blk(const int* __restrict__ indeg,
                                                  int* __restrict__ rs,
                                                  int* __restrict__ bsum) {
    __shared__ int ts[256];
    int b = blockIdx.x;
    int t = threadIdx.x;
    int base = b * SB + t * 4;
    int v[4] = {0, 0, 0, 0};
#pragma unroll
    for (int j = 0; j < 4; j++) {
        int i = base + j;
        if (i < Nn) v[j] = indeg[i];
    }
    int tsum = v[0] + v[1] + v[2] + v[3];
    ts[t] = tsum;
    __syncthreads();
    for (int off = 1; off < 256; off <<= 1) {
        int x = (t >= off) ? ts[t - off] : 0;
        __syncthreads();
        ts[t] += x;
        __syncthreads();
    }
    int run = (t == 0) ? 0 : ts[t - 1];
    if (t == 255) bsum[b] = ts[255];
#pragma unroll
    for (int j = 0; j < 4; j++) {
        int i = base + j;
        if (i < Nn) { rs[i] = run; run += v[j]; }
    }
}

// ---------------- phase 2: exclusive scan of 49 block sums (one wave) ----------------
__global__ void k_scan_top(const int* __restrict__ bsum, int* __restrict__ boff) {
    int t = threadIdx.x;              // 64 threads
    int orig = (t < NSB) ? bsum[t] : 0;
    int v = orig;
#pragma unroll
    for (int off = 1; off < 64; off <<= 1) {
        int u = __shfl_up(v, off, 64);
        if (t >= off) v += u;
    }
    if (t < NSB) boff[t] = v - orig;  // exclusive
}

// ---------------- phase 3: add block offsets ----------------
__global__ void k_scan_add(int* __restrict__ rs, const int* __restrict__ boff) {
    int i = blockIdx.x * blockDim.x + threadIdx.x;
    if (i < Nn) rs[i] += boff[i >> 10];
}

// ---------------- counting-sort fill: csr_src grouped by dst ----------------
// After this kernel rs[d] == end of segment d.
__global__ void k_fill(const int* __restrict__ ei, int* __restrict__ rs,
                       int* __restrict__ csr_src) {
    int e = blockIdx.x * blockDim.x + threadIdx.x;
    if (e >= Ee) return;
    int s = ei[e];
    int d = ei[Ee + e];
    int slot = atomicAdd(&rs[d], 1);
    csr_src[slot] = s;
}

// ---------------- GEMM: Y[N,H] = X[N,H] @ W[H,H] ----------------
__global__ __launch_bounds__(256) void k_gemm(const float* __restrict__ X,
                                              const float* __restrict__ W,
                                              float* __restrict__ Y) {
    __shared__ float ws[Hh * Hh];
    int tid = threadIdx.x;
    float4* ws4 = (float4*)ws;
    const float4* W4 = (const float4*)W;
#pragma unroll
    for (int i = 0; i < 16; i++) ws4[tid + 256 * i] = W4[tid + 256 * i];
    __syncthreads();

    int tc = tid & 31;
    int tr = tid >> 5;
    int row0 = blockIdx.x * 32 + tr * 4;

    int r[4];
#pragma unroll
    for (int i = 0; i < 4; i++) {
        int rr = row0 + i;
        r[i] = rr < Nn ? rr : (Nn - 1);
    }

    float acc[4][4] = {};
    for (int k4 = 0; k4 < Hh / 4; k4++) {
        float4 xv[4];
#pragma unroll
        for (int i = 0; i < 4; i++)
            xv[i] = ((const float4*)(X + r[i] * Hh))[k4];
#pragma unroll
        for (int kk = 0; kk < 4; kk++) {
            float4 wv = ((const float4*)(ws + (k4 * 4 + kk) * Hh))[tc];
#pragma unroll
            for (int i = 0; i < 4; i++) {
                float xs = (&xv[i].x)[kk];
                acc[i][0] += xs * wv.x;
                acc[i][1] += xs * wv.y;
                acc[i][2] += xs * wv.z;
                acc[i][3] += xs * wv.w;
            }
        }
    }
#pragma unroll
    for (int i = 0; i < 4; i++) {
        int rr = row0 + i;
        if (rr < Nn)
            ((float4*)(Y + rr * Hh))[tc] =
                make_float4(acc[i][0], acc[i][1], acc[i][2], acc[i][3]);
    }
}

// ---------------- CSR gather ----------------
__global__ __launch_bounds__(256) void k_gather(const float* __restrict__ Hb,
                                                const float* __restrict__ dis,
                                                const float* __restrict__ bias,
                                                const int* __restrict__ rs,
                                                const int* __restrict__ csr_src,
                                                float* __restrict__ A) {
    int node = blockIdx.x * 4 + (threadIdx.x >> 6);
    if (node >= Nn) return;
    int lane = threadIdx.x & 63;

    float dn = dis[node];
    float2 hs = ((const float2*)(Hb + node * Hh))[lane];
    float2 bv = ((const float2*)bias)[lane];
    float sn = dn * dn;
    float2 acc;
    acc.x = hs.x * sn + bv.x;
    acc.y = hs.y * sn + bv.y;

    int beg = (node == 0) ? 0 : rs[node - 1];
    int end = rs[node];

    int j = beg;
    for (; j + 1 < end; j += 2) {
        int s0 = csr_src[j];
        int s1 = csr_src[j + 1];
        float n0 = dis[s0] * dn;
        float n1 = dis[s1] * dn;
        float2 v0 = ((const float2*)(Hb + s0 * Hh))[lane];
        float2 v1 = ((const float2*)(Hb + s1 * Hh))[lane];
        acc.x += v0.x * n0 + v1.x * n1;
        acc.y += v0.y * n0 + v1.y * n1;
    }
    if (j < end) {
        int s0 = csr_src[j];
        float n0 = dis[s0] * dn;
        float2 v0 = ((const float2*)(Hb + s0 * Hh))[lane];
        acc.x += v0.x * n0;
        acc.y += v0.y * n0;
    }
    ((float2*)(A + node * Hh))[lane] = acc;
}

// ---------------- BN stats: per-channel sum & sumsq ----------------
__global__ __launch_bounds__(256) void k_stats(const float* __restrict__ A,
                                               float* __restrict__ stats) {
    __shared__ float s1[256], s2[256];
    int tid = threadIdx.x;
    int c = tid & 127;
    int half = tid >> 7;
    float sum = 0.f, sq = 0.f;
    for (int r = blockIdx.x * 2 + half; r < Nn; r += gridDim.x * 2) {
        float v = A[r * Hh + c];
        sum += v;
        sq += v * v;
    }
    s1[tid] = sum;
    s2[tid] = sq;
    __syncthreads();
    if (half == 0) {
        atomicAdd(&stats[c], s1[c] + s1[c + 128]);
        atomicAdd(&stats[Hh + c], s2[c] + s2[c + 128]);
    }
}

// ---------------- BN normalize + affine + relu ----------------
__global__ void k_norm(const float* __restrict__ A, const float* __restrict__ stats,
                       const float* __restrict__ gam, const float* __restrict__ bet,
                       float* __restrict__ Xo) {
    int tid = blockIdx.x * blockDim.x + threadIdx.x;
    if (tid >= Nn * 32) return;
    int c4 = tid & 31;
    float4 v = ((const float4*)A)[tid];
    float4 o;
#pragma unroll
    for (int j = 0; j < 4; j++) {
        int c = c4 * 4 + j;
        float mu = stats[c] * (1.0f / Nn);
        float var = stats[Hh + c] * (1.0f / Nn) - mu * mu;
        float istd = rsqrtf(var + EPSf);
        float val = ((&v.x)[j] - mu) * istd * gam[c] + bet[c];
        (&o.x)[j] = fmaxf(val, 0.0f);
    }
    ((float4*)Xo)[tid] = o;
}

// ---------------- segmented mean pool: one block per graph, no atomics ----------------
__global__ __launch_bounds__(128) void k_pool_seg(const float* __restrict__ X,
                                                  const int* __restrict__ gstart,
                                                  float* __restrict__ pooled) {
    int g = blockIdx.x;
    int c = threadIdx.x;
    int s = gstart[g], e = gstart[g + 1];
    float sum = 0.0f;
    for (int r = s; r < e; r++) sum += X[r * Hh + c];
    pooled[g * Hh + c] = sum;
}

// ---------------- MLP head ----------------
__global__ __launch_bounds__(128) void k_mlp(const float* __restrict__ pooled,
                                             const int* __restrict__ gstart,
                                             const float* __restrict__ W1,
                                             const float* __restrict__ b1,
                                             const float* __restrict__ W2,
                                             const float* __restrict__ b2,
                                             float* __restrict__ out) {
    int g = blockIdx.x;
    int c = threadIdx.x;
    __shared__ float p[Hh];
    __shared__ float hid[Hh];
    int n = gstart[g + 1] - gstart[g];
    float inv = 1.0f / (float)(n > 1 ? n : 1);
    p[c] = pooled[g * Hh + c] * inv;
    __syncthreads();
    float acc = b1[c];
    for (int k = 0; k < Hh; k++) acc += p[k] * W1[k * Hh + c];
    hid[c] = fmaxf(acc, 0.0f);
    __syncthreads();
    if (c < Cc) {
        float acc2 = b2[c];
        for (int k = 0; k < Hh; k++) acc2 += hid[k] * W2[k * Cc + c];
        out[g * Cc + c] = acc2;
    }
}

extern "C" void kernel_launch(void* const* d_in, const int* in_sizes, int n_in,
                              void* d_out, int out_size, void* d_ws, size_t ws_size,
                              hipStream_t stream) {
    const float* x      = (const float*)d_in[0];
    const int*   ei     = (const int*)d_in[1];
    const int*   batch  = (const int*)d_in[2];
    const float* conv_w = (const float*)d_in[3];
    const float* conv_b = (const float*)d_in[4];
    const float* bn_g   = (const float*)d_in[5];
    const float* bn_b   = (const float*)d_in[6];
    const float* w1     = (const float*)d_in[7];
    const float* b1     = (const float*)d_in[8];
    const float* w2     = (const float*)d_in[9];
    const float* b2     = (const float*)d_in[10];
    float* out = (float*)d_out;

    float* B0      = (float*)d_ws;              // N*H
    float* B1      = B0 + Nn * Hh;              // N*H
    float* dis     = B1 + Nn * Hh;              // N
    float* stats   = dis + Nn;                  // 2*H
    float* pooled  = stats + 2 * Hh;            // G*H
    int*   indeg   = (int*)(pooled + Gg * Hh);  // N
    int*   rs      = indeg + Nn;                // N
    int*   gstart  = rs + Nn;                   // G+1
    int*   bsum    = gstart + Gg + 1;           // NSB
    int*   boff    = bsum + NSB;                // NSB
    int*   csr_src = boff + NSB;                // E

    // ---- CSR build + graph bounds (per launch; ws re-poisoned every call) ----
    k_init<<<(Nn + 255) / 256, 256, 0, stream>>>(indeg);
    k_deg<<<(Ee + 255) / 256, 256, 0, stream>>>(ei, indeg);
    k_deg_fin<<<(Nn + 255) / 256, 256, 0, stream>>>(indeg, dis);
    k_gbounds<<<(Gg + 256) / 256, 256, 0, stream>>>(batch, gstart);
    k_scan_blk<<<NSB, 256, 0, stream>>>(indeg, rs, bsum);
    k_scan_top<<<1, 64, 0, stream>>>(bsum, boff);
    k_scan_add<<<(Nn + 255) / 256, 256, 0, stream>>>(rs, boff);
    k_fill<<<(Ee + 255) / 256, 256, 0, stream>>>(ei, rs, csr_src);

    const float* cur = x;
    for (int l = 0; l < 3; l++) {
        k_gemm<<<(Nn + 31) / 32, 256, 0, stream>>>(cur, conv_w + l * Hh * Hh, B0);
        k_gather<<<(Nn + 3) / 4, 256, 0, stream>>>(B0, dis, conv_b + l * Hh, rs,
                                                   csr_src, B1);
        hipMemsetAsync(stats, 0, 2 * Hh * sizeof(float), stream);
        k_stats<<<256, 256, 0, stream>>>(B1, stats);
        k_norm<<<(Nn * 32 + 255) / 256, 256, 0, stream>>>(B1, stats, bn_g + l * Hh,
                                                          bn_b + l * Hh, B1);
        cur = B1;
    }

    k_pool_seg<<<Gg, 128, 0, stream>>>(B1, gstart, pooled);
    k_mlp<<<Gg, 128, 0, stream>>>(pooled, gstart, w1, b1, w2, b2, out);
}

// Round 5
// 561.354 us; speedup vs baseline: 8.2447x; 1.1531x over previous
//
#include <hip/hip_runtime.h>

#define Nn 50000
#define Ee 800000
#define Gg 1000
#define Hh 128
#define Cc 6
#define EPSf 1e-5f
#define SB 1024                       // elements per scan block
#define NSB ((Nn + SB - 1) / SB)      // 49

typedef unsigned short u16;
typedef unsigned int u32;

static __device__ inline u16 f2bf(float f) {
    u32 u = __float_as_uint(f);
    u32 r = (u + 0x7fffu + ((u >> 16) & 1u)) >> 16;   // RNE
    return (u16)r;
}
static __device__ inline float bf_lo(u32 v) { return __uint_as_float(v << 16); }
static __device__ inline float bf_hi(u32 v) { return __uint_as_float(v & 0xffff0000u); }

// ---------------- init: zero indeg + per-layer stats ----------------
__global__ void k_init(int* __restrict__ indeg, float* __restrict__ stats3) {
    int i = blockIdx.x * blockDim.x + threadIdx.x;
    if (i < Nn) indeg[i] = 0;
    if (i < 3 * 2 * Hh) stats3[i] = 0.0f;
}

// ---------------- in-degree histogram ----------------
__global__ void k_deg(const int* __restrict__ ei, int* __restrict__ indeg) {
    int e = blockIdx.x * blockDim.x + threadIdx.x;
    if (e < Ee) atomicAdd(&indeg[ei[Ee + e]], 1);
}

// ---------------- dis = rsqrt(deg+1)  +  graph bounds (fused) ----------------
__global__ void k_prep(const int* __restrict__ indeg, float* __restrict__ dis,
                       const int* __restrict__ batch, int* __restrict__ gstart) {
    int i = blockIdx.x * blockDim.x + threadIdx.x;
    if (i < Nn) dis[i] = rsqrtf((float)indeg[i] + 1.0f);
    if (i <= Gg) {
        int lo = 0, hi = Nn;
        while (lo < hi) {
            int mid = (lo + hi) >> 1;
            if (batch[mid] < i) lo = mid + 1; else hi = mid;
        }
        gstart[i] = lo;
    }
}

// ---------------- multi-block exclusive scan: phase 1 ----------------
__global__ __launch_bounds__(256) void k_scan_blk(const int* __restrict__ indeg,
                                                  int* __restrict__ rs,
                                                  int* __restrict__ bsum) {
    __shared__ int ts[256];
    int b = blockIdx.x;
    int t = threadIdx.x;
    int base = b * SB + t * 4;
    int v[4] = {0, 0, 0, 0};
#pragma unroll
    for (int j = 0; j < 4; j++) {
        int i = base + j;
        if (i < Nn) v[j] = indeg[i];
    }
    int tsum = v[0] + v[1] + v[2] + v[3];
    ts[t] = tsum;
    __syncthreads();
    for (int off = 1; off < 256; off <<= 1) {
        int x = (t >= off) ? ts[t - off] : 0;
        __syncthreads();
        ts[t] += x;
        __syncthreads();
    }
    int run = (t == 0) ? 0 : ts[t - 1];
    if (t == 255) bsum[b] = ts[255];
#pragma unroll
    for (int j = 0; j < 4; j++) {
        int i = base + j;
        if (i < Nn) { rs[i] = run; run += v[j]; }
    }
}

// ---------------- phase 2: exclusive scan of block sums (one wave) ----------------
__global__ void k_scan_top(const int* __restrict__ bsum, int* __restrict__ boff) {
    int t = threadIdx.x;              // 64 threads
    int orig = (t < NSB) ? bsum[t] : 0;
    int v = orig;
#pragma unroll
    for (int off = 1; off < 64; off <<= 1) {
        int u = __shfl_up(v, off, 64);
        if (t >= off) v += u;
    }
    if (t < NSB) boff[t] = v - orig;  // exclusive
}

// ---------------- phase 3: add block offsets ----------------
__global__ void k_scan_add(int* __restrict__ rs, const int* __restrict__ boff) {
    int i = blockIdx.x * blockDim.x + threadIdx.x;
    if (i < Nn) rs[i] += boff[i >> 10];
}

// ---------------- counting-sort fill: src + edge weight grouped by dst ----------------
// After this kernel rs[d] == end of segment d.
__global__ void k_fill(const int* __restrict__ ei, int* __restrict__ rs,
                       const float* __restrict__ dis,
                       int* __restrict__ csr_src, float* __restrict__ csr_w) {
    int e = blockIdx.x * blockDim.x + threadIdx.x;
    if (e >= Ee) return;
    int s = ei[e];
    int d = ei[Ee + e];
    int slot = atomicAdd(&rs[d], 1);
    csr_src[slot] = s;
    csr_w[slot] = dis[s] * dis[d];
}

// ---------------- GEMM: Yh[N,H](bf16) = X[N,H](fp32) @ W[H,H] ----------------
__global__ __launch_bounds__(256) void k_gemm(const float* __restrict__ X,
                                              const float* __restrict__ W,
                                              u16* __restrict__ Yh) {
    __shared__ float ws[Hh * Hh];
    int tid = threadIdx.x;
    float4* ws4 = (float4*)ws;
    const float4* W4 = (const float4*)W;
#pragma unroll
    for (int i = 0; i < 16; i++) ws4[tid + 256 * i] = W4[tid + 256 * i];
    __syncthreads();

    int tc = tid & 31;
    int tr = tid >> 5;
    int row0 = blockIdx.x * 32 + tr * 4;

    int r[4];
#pragma unroll
    for (int i = 0; i < 4; i++) {
        int rr = row0 + i;
        r[i] = rr < Nn ? rr : (Nn - 1);
    }

    float acc[4][4] = {};
    for (int k4 = 0; k4 < Hh / 4; k4++) {
        float4 xv[4];
#pragma unroll
        for (int i = 0; i < 4; i++)
            xv[i] = ((const float4*)(X + r[i] * Hh))[k4];
#pragma unroll
        for (int kk = 0; kk < 4; kk++) {
            float4 wv = ((const float4*)(ws + (k4 * 4 + kk) * Hh))[tc];
#pragma unroll
            for (int i = 0; i < 4; i++) {
                float xs = (&xv[i].x)[kk];
                acc[i][0] += xs * wv.x;
                acc[i][1] += xs * wv.y;
                acc[i][2] += xs * wv.z;
                acc[i][3] += xs * wv.w;
            }
        }
    }
#pragma unroll
    for (int i = 0; i < 4; i++) {
        int rr = row0 + i;
        if (rr < Nn) {
            ushort4 o;
            o.x = f2bf(acc[i][0]);
            o.y = f2bf(acc[i][1]);
            o.z = f2bf(acc[i][2]);
            o.w = f2bf(acc[i][3]);
            ((ushort4*)(Yh + rr * Hh))[tc] = o;
        }
    }
}

// ---------------- CSR gather: bf16 rows, fp32 accumulate ----------------
// One wave per node; lane covers 2 channels (one u32 = 2 bf16).
__global__ __launch_bounds__(256) void k_gather(const u16* __restrict__ Hb,
                                                const float* __restrict__ dis,
                                                const float* __restrict__ bias,
                                                const int* __restrict__ rs,
                                                const int* __restrict__ csr_src,
                                                const float* __restrict__ csr_w,
                                                float* __restrict__ A) {
    int node = blockIdx.x * 4 + (threadIdx.x >> 6);
    if (node >= Nn) return;
    int lane = threadIdx.x & 63;

    float dn = dis[node];
    u32 hv = ((const u32*)(Hb + node * Hh))[lane];
    float2 bv = ((const float2*)bias)[lane];
    float sn = dn * dn;
    float2 acc;
    acc.x = bf_lo(hv) * sn + bv.x;
    acc.y = bf_hi(hv) * sn + bv.y;

    int beg = (node == 0) ? 0 : rs[node - 1];
    int end = rs[node];

    int j = beg;
    for (; j + 3 < end; j += 4) {
        int s0 = csr_src[j],     s1 = csr_src[j + 1];
        int s2 = csr_src[j + 2], s3 = csr_src[j + 3];
        float w0 = csr_w[j],     w1 = csr_w[j + 1];
        float w2 = csr_w[j + 2], w3 = csr_w[j + 3];
        u32 v0 = ((const u32*)(Hb + s0 * Hh))[lane];
        u32 v1 = ((const u32*)(Hb + s1 * Hh))[lane];
        u32 v2 = ((const u32*)(Hb + s2 * Hh))[lane];
        u32 v3 = ((const u32*)(Hb + s3 * Hh))[lane];
        acc.x += bf_lo(v0) * w0 + bf_lo(v1) * w1 + bf_lo(v2) * w2 + bf_lo(v3) * w3;
        acc.y += bf_hi(v0) * w0 + bf_hi(v1) * w1 + bf_hi(v2) * w2 + bf_hi(v3) * w3;
    }
    for (; j < end; j++) {
        int s0 = csr_src[j];
        float w0 = csr_w[j];
        u32 v0 = ((const u32*)(Hb + s0 * Hh))[lane];
        acc.x += bf_lo(v0) * w0;
        acc.y += bf_hi(v0) * w0;
    }
    ((float2*)(A + node * Hh))[lane] = acc;
}

// ---------------- BN stats: per-channel sum & sumsq ----------------
__global__ __launch_bounds__(256) void k_stats(const float* __restrict__ A,
                                               float* __restrict__ stats) {
    __shared__ float s1[256], s2[256];
    int tid = threadIdx.x;
    int c = tid & 127;
    int half = tid >> 7;
    float sum = 0.f, sq = 0.f;
    for (int r = blockIdx.x * 2 + half; r < Nn; r += gridDim.x * 2) {
        float v = A[r * Hh + c];
        sum += v;
        sq += v * v;
    }
    s1[tid] = sum;
    s2[tid] = sq;
    __syncthreads();
    if (half == 0) {
        atomicAdd(&stats[c], s1[c] + s1[c + 128]);
        atomicAdd(&stats[Hh + c], s2[c] + s2[c + 128]);
    }
}

// ---------------- BN normalize + affine + relu ----------------
__global__ void k_norm(const float* __restrict__ A, const float* __restrict__ stats,
                       const float* __restrict__ gam, const float* __restrict__ bet,
                       float* __restrict__ Xo) {
    int tid = blockIdx.x * blockDim.x + threadIdx.x;
    if (tid >= Nn * 32) return;
    int c4 = tid & 31;
    float4 v = ((const float4*)A)[tid];
    float4 o;
#pragma unroll
    for (int j = 0; j < 4; j++) {
        int c = c4 * 4 + j;
        float mu = stats[c] * (1.0f / Nn);
        float var = stats[Hh + c] * (1.0f / Nn) - mu * mu;
        float istd = rsqrtf(var + EPSf);
        float val = ((&v.x)[j] - mu) * istd * gam[c] + bet[c];
        (&o.x)[j] = fmaxf(val, 0.0f);
    }
    ((float4*)Xo)[tid] = o;
}

// ---------------- segmented mean pool: one block per graph, no atomics ----------------
__global__ __launch_bounds__(128) void k_pool_seg(const float* __restrict__ X,
                                                  const int* __restrict__ gstart,
                                                  float* __restrict__ pooled) {
    int g = blockIdx.x;
    int c = threadIdx.x;
    int s = gstart[g], e = gstart[g + 1];
    float sum = 0.0f;
    for (int r = s; r < e; r++) sum += X[r * Hh + c];
    pooled[g * Hh + c] = sum;
}

// ---------------- MLP head ----------------
__global__ __launch_bounds__(128) void k_mlp(const float* __restrict__ pooled,
                                             const int* __restrict__ gstart,
                                             const float* __restrict__ W1,
                                             const float* __restrict__ b1,
                                             const float* __restrict__ W2,
                                             const float* __restrict__ b2,
                                             float* __restrict__ out) {
    int g = blockIdx.x;
    int c = threadIdx.x;
    __shared__ float p[Hh];
    __shared__ float hid[Hh];
    int n = gstart[g + 1] - gstart[g];
    float inv = 1.0f / (float)(n > 1 ? n : 1);
    p[c] = pooled[g * Hh + c] * inv;
    __syncthreads();
    float acc = b1[c];
    for (int k = 0; k < Hh; k++) acc += p[k] * W1[k * Hh + c];
    hid[c] = fmaxf(acc, 0.0f);
    __syncthreads();
    if (c < Cc) {
        float acc2 = b2[c];
        for (int k = 0; k < Hh; k++) acc2 += hid[k] * W2[k * Cc + c];
        out[g * Cc + c] = acc2;
    }
}

extern "C" void kernel_launch(void* const* d_in, const int* in_sizes, int n_in,
                              void* d_out, int out_size, void* d_ws, size_t ws_size,
                              hipStream_t stream) {
    const float* x      = (const float*)d_in[0];
    const int*   ei     = (const int*)d_in[1];
    const int*   batch  = (const int*)d_in[2];
    const float* conv_w = (const float*)d_in[3];
    const float* conv_b = (const float*)d_in[4];
    const float* bn_g   = (const float*)d_in[5];
    const float* bn_b   = (const float*)d_in[6];
    const float* w1     = (const float*)d_in[7];
    const float* b1     = (const float*)d_in[8];
    const float* w2     = (const float*)d_in[9];
    const float* b2     = (const float*)d_in[10];
    float* out = (float*)d_out;

    float* B1      = (float*)d_ws;              // N*H fp32 (agg / normalized x)
    u16*   B0h     = (u16*)(B1 + Nn * Hh);      // N*H bf16 (GEMM out, gather src)
    float* dis     = (float*)(B0h + Nn * Hh);   // N
    float* stats3  = dis + Nn;                  // 3*2*H
    float* pooled  = stats3 + 3 * 2 * Hh;       // G*H
    int*   indeg   = (int*)(pooled + Gg * Hh);  // N
    int*   rs      = indeg + Nn;                // N
    int*   gstart  = rs + Nn;                   // G+1
    int*   bsum    = gstart + Gg + 1;           // NSB
    int*   boff    = bsum + NSB;                // NSB
    int*   csr_src = boff + NSB;                // E
    float* csr_w   = (float*)(csr_src + Ee);    // E

    // ---- CSR build + graph bounds (per launch; ws re-poisoned every call) ----
    k_init<<<(Nn + 255) / 256, 256, 0, stream>>>(indeg, stats3);
    k_deg<<<(Ee + 255) / 256, 256, 0, stream>>>(ei, indeg);
    k_prep<<<(Nn + 255) / 256, 256, 0, stream>>>(indeg, dis, batch, gstart);
    k_scan_blk<<<NSB, 256, 0, stream>>>(indeg, rs, bsum);
    k_scan_top<<<1, 64, 0, stream>>>(bsum, boff);
    k_scan_add<<<(Nn + 255) / 256, 256, 0, stream>>>(rs, boff);
    k_fill<<<(Ee + 255) / 256, 256, 0, stream>>>(ei, rs, dis, csr_src, csr_w);

    const float* cur = x;
    for (int l = 0; l < 3; l++) {
        float* stats = stats3 + l * 2 * Hh;
        k_gemm<<<(Nn + 31) / 32, 256, 0, stream>>>(cur, conv_w + l * Hh * Hh, B0h);
        k_gather<<<(Nn + 3) / 4, 256, 0, stream>>>(B0h, dis, conv_b + l * Hh, rs,
                                                   csr_src, csr_w, B1);
        k_stats<<<256, 256, 0, stream>>>(B1, stats);
        k_norm<<<(Nn * 32 + 255) / 256, 256, 0, stream>>>(B1, stats, bn_g + l * Hh,
                                                          bn_b + l * Hh, B1);
        cur = B1;
    }

    k_pool_seg<<<Gg, 128, 0, stream>>>(B1, gstart, pooled);
    k_mlp<<<Gg, 128, 0, stream>>>(pooled, gstart, w1, b1, w2, b2, out);
}

// Round 6
// 474.054 us; speedup vs baseline: 9.7630x; 1.1842x over previous
//
#include <hip/hip_runtime.h>

#define Nn 50000
#define Ee 800000
#define Gg 1000
#define Hh 128
#define Cc 6
#define EPSf 1e-5f
#define SB 1024                       // elements per scan block
#define NSB ((Nn + SB - 1) / SB)      // 49

typedef unsigned short u16;
typedef unsigned int u32;
typedef __attribute__((ext_vector_type(8))) short bf16x8;
typedef __attribute__((ext_vector_type(4))) float f32x4;

struct alignas(8) Edge { int s; float w; };

static __device__ inline u16 f2bf(float f) {
    u32 u = __float_as_uint(f);
    u32 r = (u + 0x7fffu + ((u >> 16) & 1u)) >> 16;   // RNE
    return (u16)r;
}
static __device__ inline float bf_lo(u32 v) { return __uint_as_float(v << 16); }
static __device__ inline float bf_hi(u32 v) { return __uint_as_float(v & 0xffff0000u); }

// ---------------- init: zero indeg + per-layer stats ----------------
__global__ void k_init(int* __restrict__ indeg, float* __restrict__ stats3) {
    int i = blockIdx.x * blockDim.x + threadIdx.x;
    if (i < Nn) indeg[i] = 0;
    if (i < 3 * 2 * Hh) stats3[i] = 0.0f;
}

// ---------------- in-degree histogram ----------------
__global__ void k_deg(const int* __restrict__ ei, int* __restrict__ indeg) {
    int e = blockIdx.x * blockDim.x + threadIdx.x;
    if (e < Ee) atomicAdd(&indeg[ei[Ee + e]], 1);
}

// ---------------- dis = rsqrt(deg+1)  +  graph bounds (fused) ----------------
__global__ void k_prep(const int* __restrict__ indeg, float* __restrict__ dis,
                       const int* __restrict__ batch, int* __restrict__ gstart) {
    int i = blockIdx.x * blockDim.x + threadIdx.x;
    if (i < Nn) dis[i] = rsqrtf((float)indeg[i] + 1.0f);
    if (i <= Gg) {
        int lo = 0, hi = Nn;
        while (lo < hi) {
            int mid = (lo + hi) >> 1;
            if (batch[mid] < i) lo = mid + 1; else hi = mid;
        }
        gstart[i] = lo;
    }
}

// ---------------- multi-block exclusive scan: phase 1 ----------------
__global__ __launch_bounds__(256) void k_scan_blk(const int* __restrict__ indeg,
                                                  int* __restrict__ rs,
                                                  int* __restrict__ bsum) {
    __shared__ int ts[256];
    int b = blockIdx.x;
    int t = threadIdx.x;
    int base = b * SB + t * 4;
    int v[4] = {0, 0, 0, 0};
#pragma unroll
    for (int j = 0; j < 4; j++) {
        int i = base + j;
        if (i < Nn) v[j] = indeg[i];
    }
    int tsum = v[0] + v[1] + v[2] + v[3];
    ts[t] = tsum;
    __syncthreads();
    for (int off = 1; off < 256; off <<= 1) {
        int x = (t >= off) ? ts[t - off] : 0;
        __syncthreads();
        ts[t] += x;
        __syncthreads();
    }
    int run = (t == 0) ? 0 : ts[t - 1];
    if (t == 255) bsum[b] = ts[255];
#pragma unroll
    for (int j = 0; j < 4; j++) {
        int i = base + j;
        if (i < Nn) { rs[i] = run; run += v[j]; }
    }
}

// ---------------- phase 2: exclusive scan of block sums (one wave) ----------------
__global__ void k_scan_top(const int* __restrict__ bsum, int* __restrict__ boff) {
    int t = threadIdx.x;              // 64 threads
    int orig = (t < NSB) ? bsum[t] : 0;
    int v = orig;
#pragma unroll
    for (int off = 1; off < 64; off <<= 1) {
        int u = __shfl_up(v, off, 64);
        if (t >= off) v += u;
    }
    if (t < NSB) boff[t] = v - orig;  // exclusive
}

// ---------------- phase 3: add block offsets ----------------
__global__ void k_scan_add(int* __restrict__ rs, const int* __restrict__ boff) {
    int i = blockIdx.x * blockDim.x + threadIdx.x;
    if (i < Nn) rs[i] += boff[i >> 10];
}

// ---------------- counting-sort fill: packed {src,weight} grouped by dst ----------------
// Single 8B scattered store per edge. After this kernel rs[d] == end of segment d.
__global__ void k_fill(const int* __restrict__ ei, int* __restrict__ rs,
                       const float* __restrict__ dis, Edge* __restrict__ edges) {
    int e = blockIdx.x * blockDim.x + threadIdx.x;
    if (e >= Ee) return;
    int s = ei[e];
    int d = ei[Ee + e];
    int slot = atomicAdd(&rs[d], 1);
    Edge ed; ed.s = s; ed.w = dis[s] * dis[d];
    edges[slot] = ed;
}

// ---------------- one-time: conv_w fp32 [l][k][n] -> bf16 W^T [l][n][k] ----------------
__global__ __launch_bounds__(256) void k_wt(const float* __restrict__ W3,
                                            u16* __restrict__ WT3) {
    __shared__ u16 t[Hh * 136];
    int l = blockIdx.x;
    const float* W = W3 + l * Hh * Hh;
    u16* WT = WT3 + l * Hh * Hh;
    int tid = threadIdx.x;
#pragma unroll
    for (int i = 0; i < 16; i++) {
        int v = tid + 256 * i;            // float4 idx over 4096
        int r = v >> 5, c4 = v & 31;
        float4 d = ((const float4*)W)[v];
        u16* p = t + r * 136 + c4 * 4;
        p[0] = f2bf(d.x); p[1] = f2bf(d.y); p[2] = f2bf(d.z); p[3] = f2bf(d.w);
    }
    __syncthreads();
#pragma unroll
    for (int i = 0; i < 64; i++) {
        int o = tid + 256 * i;            // u16 idx over 16384
        int n = o >> 7, k = o & 127;
        WT[o] = t[k * 136 + n];
    }
}

// ---------------- cast x fp32 -> bf16 ----------------
__global__ void k_cast(const float* __restrict__ X, u16* __restrict__ Xh) {
    int tid = blockIdx.x * blockDim.x + threadIdx.x;
    if (tid >= Nn * 32) return;
    float4 v = ((const float4*)X)[tid];
    ushort4 o;
    o.x = f2bf(v.x); o.y = f2bf(v.y); o.z = f2bf(v.z); o.w = f2bf(v.w);
    ((ushort4*)Xh)[tid] = o;
}

// ---------------- MFMA GEMM: Yh[N,H](bf16) = Xh[N,H](bf16) @ W ----------------
// 256 thr = 4 waves; 64 rows/block (16/wave); 8 N-tiles/wave; K=128 via 4 MFMA steps.
// A-frag: lane holds X[row0+(l&15)][k0+(l>>4)*8 + 0..7]; B-frag mirrored from LDS W^T.
// C/D: col=lane&15, row=(lane>>4)*4+reg  [m89-verified].
__global__ __launch_bounds__(256) void k_gemm(const u16* __restrict__ Xh,
                                              const u16* __restrict__ WT,
                                              u16* __restrict__ Yh) {
    __shared__ u16 wt[Hh * 136];
    int tid = threadIdx.x;
    // stage W^T (16KB bf16 -> LDS stride 136, 2-way banked = free)
#pragma unroll
    for (int i = 0; i < 8; i++) {
        int v = tid + 256 * i;            // uint4 idx over 2048
        int n = v >> 4, k8 = v & 15;
        uint4 d = ((const uint4*)WT)[v];
        *((uint4*)(wt + n * 136 + k8 * 8)) = d;
    }
    __syncthreads();

    int wv = tid >> 6, lane = tid & 63;
    int m = lane & 15, q = lane >> 4;
    int row0 = blockIdx.x * 64 + wv * 16;
    int lrow = row0 + m;
    if (lrow >= Nn) lrow = Nn - 1;        // clamp load row; stores guarded
    const u16* xrow = Xh + lrow * Hh + q * 8;

    f32x4 acc[8] = {};
#pragma unroll
    for (int k0 = 0; k0 < Hh; k0 += 32) {
        bf16x8 a = *(const bf16x8*)(xrow + k0);
#pragma unroll
        for (int t = 0; t < 8; t++) {
            bf16x8 b = *(const bf16x8*)(wt + (t * 16 + m) * 136 + k0 + q * 8);
            acc[t] = __builtin_amdgcn_mfma_f32_16x16x32_bf16(a, b, acc[t], 0, 0, 0);
        }
    }

    int orow0 = row0 + q * 4;
#pragma unroll
    for (int t = 0; t < 8; t++) {
#pragma unroll
        for (int r = 0; r < 4; r++) {
            int rr = orow0 + r;
            if (rr < Nn) Yh[rr * Hh + t * 16 + m] = f2bf(acc[t][r]);
        }
    }
}

// ---------------- CSR gather: bf16 rows, packed edges, fp32 accumulate ----------------
__global__ __launch_bounds__(256) void k_gather(const u16* __restrict__ Hb,
                                                const float* __restrict__ dis,
                                                const float* __restrict__ bias,
                                                const int* __restrict__ rs,
                                                const Edge* __restrict__ edges,
                                                float* __restrict__ A) {
    int node = blockIdx.x * 4 + (threadIdx.x >> 6);
    if (node >= Nn) return;
    int lane = threadIdx.x & 63;

    float dn = dis[node];
    u32 hv = ((const u32*)(Hb + node * Hh))[lane];
    float2 bv = ((const float2*)bias)[lane];
    float sn = dn * dn;
    float2 acc;
    acc.x = bf_lo(hv) * sn + bv.x;
    acc.y = bf_hi(hv) * sn + bv.y;

    int beg = (node == 0) ? 0 : rs[node - 1];
    int end = rs[node];

    int j = beg;
    for (; j + 3 < end; j += 4) {
        Edge e0 = edges[j],     e1 = edges[j + 1];
        Edge e2 = edges[j + 2], e3 = edges[j + 3];
        u32 v0 = ((const u32*)(Hb + e0.s * Hh))[lane];
        u32 v1 = ((const u32*)(Hb + e1.s * Hh))[lane];
        u32 v2 = ((const u32*)(Hb + e2.s * Hh))[lane];
        u32 v3 = ((const u32*)(Hb + e3.s * Hh))[lane];
        acc.x += bf_lo(v0) * e0.w + bf_lo(v1) * e1.w + bf_lo(v2) * e2.w + bf_lo(v3) * e3.w;
        acc.y += bf_hi(v0) * e0.w + bf_hi(v1) * e1.w + bf_hi(v2) * e2.w + bf_hi(v3) * e3.w;
    }
    for (; j < end; j++) {
        Edge e0 = edges[j];
        u32 v0 = ((const u32*)(Hb + e0.s * Hh))[lane];
        acc.x += bf_lo(v0) * e0.w;
        acc.y += bf_hi(v0) * e0.w;
    }
    ((float2*)(A + node * Hh))[lane] = acc;
}

// ---------------- BN stats: per-channel sum & sumsq ----------------
__global__ __launch_bounds__(256) void k_stats(const float* __restrict__ A,
                                               float* __restrict__ stats) {
    __shared__ float s1[256], s2[256];
    int tid = threadIdx.x;
    int c = tid & 127;
    int half = tid >> 7;
    float sum = 0.f, sq = 0.f;
    for (int r = blockIdx.x * 2 + half; r < Nn; r += gridDim.x * 2) {
        float v = A[r * Hh + c];
        sum += v;
        sq += v * v;
    }
    s1[tid] = sum;
    s2[tid] = sq;
    __syncthreads();
    if (half == 0) {
        atomicAdd(&stats[c], s1[c] + s1[c + 128]);
        atomicAdd(&stats[Hh + c], s2[c] + s2[c + 128]);
    }
}

// ---------------- BN normalize + affine + relu; emit bf16 (next gemm) and/or fp32 ----------------
__global__ void k_norm(const float* __restrict__ A, const float* __restrict__ stats,
                       const float* __restrict__ gam, const float* __restrict__ bet,
                       float* __restrict__ Xo, u16* __restrict__ Xh, int wf32) {
    int tid = blockIdx.x * blockDim.x + threadIdx.x;
    if (tid >= Nn * 32) return;
    int c4 = tid & 31;
    float4 v = ((const float4*)A)[tid];
    float4 o;
#pragma unroll
    for (int j = 0; j < 4; j++) {
        int c = c4 * 4 + j;
        float mu = stats[c] * (1.0f / Nn);
        float var = stats[Hh + c] * (1.0f / Nn) - mu * mu;
        float istd = rsqrtf(var + EPSf);
        float val = ((&v.x)[j] - mu) * istd * gam[c] + bet[c];
        (&o.x)[j] = fmaxf(val, 0.0f);
    }
    if (wf32) ((float4*)Xo)[tid] = o;
    if (Xh) {
        ushort4 h;
        h.x = f2bf(o.x); h.y = f2bf(o.y); h.z = f2bf(o.z); h.w = f2bf(o.w);
        ((ushort4*)Xh)[tid] = h;
    }
}

// ---------------- segmented mean pool: one block per graph, no atomics ----------------
__global__ __launch_bounds__(128) void k_pool_seg(const float* __restrict__ X,
                                                  const int* __restrict__ gstart,
                                                  float* __restrict__ pooled) {
    int g = blockIdx.x;
    int c = threadIdx.x;
    int s = gstart[g], e = gstart[g + 1];
    float sum = 0.0f;
    for (int r = s; r < e; r++) sum += X[r * Hh + c];
    pooled[g * Hh + c] = sum;
}

// ---------------- MLP head ----------------
__global__ __launch_bounds__(128) void k_mlp(const float* __restrict__ pooled,
                                             const int* __restrict__ gstart,
                                             const float* __restrict__ W1,
                                             const float* __restrict__ b1,
                                             const float* __restrict__ W2,
                                             const float* __restrict__ b2,
                                             float* __restrict__ out) {
    int g = blockIdx.x;
    int c = threadIdx.x;
    __shared__ float p[Hh];
    __shared__ float hid[Hh];
    int n = gstart[g + 1] - gstart[g];
    float inv = 1.0f / (float)(n > 1 ? n : 1);
    p[c] = pooled[g * Hh + c] * inv;
    __syncthreads();
    float acc = b1[c];
    for (int k = 0; k < Hh; k++) acc += p[k] * W1[k * Hh + c];
    hid[c] = fmaxf(acc, 0.0f);
    __syncthreads();
    if (c < Cc) {
        float acc2 = b2[c];
        for (int k = 0; k < Hh; k++) acc2 += hid[k] * W2[k * Cc + c];
        out[g * Cc + c] = acc2;
    }
}

extern "C" void kernel_launch(void* const* d_in, const int* in_sizes, int n_in,
                              void* d_out, int out_size, void* d_ws, size_t ws_size,
                              hipStream_t stream) {
    const float* x      = (const float*)d_in[0];
    const int*   ei     = (const int*)d_in[1];
    const int*   batch  = (const int*)d_in[2];
    const float* conv_w = (const float*)d_in[3];
    const float* conv_b = (const float*)d_in[4];
    const float* bn_g   = (const float*)d_in[5];
    const float* bn_b   = (const float*)d_in[6];
    const float* w1     = (const float*)d_in[7];
    const float* b1     = (const float*)d_in[8];
    const float* w2     = (const float*)d_in[9];
    const float* b2     = (const float*)d_in[10];
    float* out = (float*)d_out;

    float* B1      = (float*)d_ws;              // N*H fp32 (agg; final normalized x)
    u16*   Xh      = (u16*)(B1 + Nn * Hh);      // N*H bf16 (gemm input)
    u16*   Yh      = Xh + Nn * Hh;              // N*H bf16 (gemm out, gather src)
    u16*   WT      = Yh + Nn * Hh;              // 3*H*H bf16 (W^T)
    float* dis     = (float*)(WT + 3 * Hh * Hh);// N
    float* stats3  = dis + Nn;                  // 3*2*H
    float* pooled  = stats3 + 3 * 2 * Hh;       // G*H
    int*   indeg   = (int*)(pooled + Gg * Hh);  // N
    int*   rs      = indeg + Nn;                // N
    int*   gstart  = rs + Nn;                   // G+1
    int*   bsum    = gstart + Gg + 1;           // NSB
    int*   boff    = bsum + NSB;                // NSB
    uintptr_t ep   = (uintptr_t)(boff + NSB);
    Edge*  edges   = (Edge*)((ep + 7) & ~(uintptr_t)7);   // E packed records

    // ---- CSR build + graph bounds + weight transpose (per launch) ----
    k_init<<<(Nn + 255) / 256, 256, 0, stream>>>(indeg, stats3);
    k_deg<<<(Ee + 255) / 256, 256, 0, stream>>>(ei, indeg);
    k_prep<<<(Nn + 255) / 256, 256, 0, stream>>>(indeg, dis, batch, gstart);
    k_scan_blk<<<NSB, 256, 0, stream>>>(indeg, rs, bsum);
    k_scan_top<<<1, 64, 0, stream>>>(bsum, boff);
    k_scan_add<<<(Nn + 255) / 256, 256, 0, stream>>>(rs, boff);
    k_fill<<<(Ee + 255) / 256, 256, 0, stream>>>(ei, rs, dis, edges);
    k_wt<<<3, 256, 0, stream>>>(conv_w, WT);
    k_cast<<<(Nn * 32 + 255) / 256, 256, 0, stream>>>(x, Xh);

    for (int l = 0; l < 3; l++) {
        float* stats = stats3 + l * 2 * Hh;
        k_gemm<<<(Nn + 63) / 64, 256, 0, stream>>>(Xh, WT + l * Hh * Hh, Yh);
        k_gather<<<(Nn + 3) / 4, 256, 0, stream>>>(Yh, dis, conv_b + l * Hh, rs,
                                                   edges, B1);
        k_stats<<<256, 256, 0, stream>>>(B1, stats);
        k_norm<<<(Nn * 32 + 255) / 256, 256, 0, stream>>>(
            B1, stats, bn_g + l * Hh, bn_b + l * Hh,
            B1, (l < 2) ? Xh : (u16*)nullptr, (l == 2) ? 1 : 0);
    }

    k_pool_seg<<<Gg, 128, 0, stream>>>(B1, gstart, pooled);
    k_mlp<<<Gg, 128, 0, stream>>>(pooled, gstart, w1, b1, w2, b2, out);
}

// Round 7
// 471.102 us; speedup vs baseline: 9.8242x; 1.0063x over previous
//
#include <hip/hip_runtime.h>

#define Nn 50000
#define Ee 800000
#define Gg 1000
#define Hh 128
#define Cc 6
#define EPSf 1e-5f
#define SB 1024                       // elements per scan block
#define NSB ((Nn + SB - 1) / SB)      // 49

typedef unsigned short u16;
typedef unsigned int u32;
typedef unsigned long long u64;
typedef __attribute__((ext_vector_type(8))) short bf16x8;
typedef __attribute__((ext_vector_type(4))) float f32x4;

struct alignas(8) Edge { int s; float w; };

static __device__ inline u16 f2bf(float f) {
    u32 u = __float_as_uint(f);
    u32 r = (u + 0x7fffu + ((u >> 16) & 1u)) >> 16;   // RNE
    return (u16)r;
}
static __device__ inline float bf_lo(u32 v) { return __uint_as_float(v << 16); }
static __device__ inline float bf_hi(u32 v) { return __uint_as_float(v & 0xffff0000u); }

// ---------------- fused prologue: zero indeg+stats, cast x->bf16, W->bf16 W^T ----------------
// grid = (Nn*32+255)/256 blocks; blocks 0..2 additionally transpose conv_w layer blockIdx.
__global__ __launch_bounds__(256) void k_pre(const float* __restrict__ X,
                                             u16* __restrict__ Xh,
                                             const float* __restrict__ W3,
                                             u16* __restrict__ WT3,
                                             int* __restrict__ indeg,
                                             float* __restrict__ stats3) {
    int t = blockIdx.x * blockDim.x + threadIdx.x;
    if (t < Nn * 32) {                 // cast x (float4 granular)
        float4 v = ((const float4*)X)[t];
        ushort4 o;
        o.x = f2bf(v.x); o.y = f2bf(v.y); o.z = f2bf(v.z); o.w = f2bf(v.w);
        ((ushort4*)Xh)[t] = o;
    }
    if (t < Nn) indeg[t] = 0;
    if (t < 3 * 2 * Hh) stats3[t] = 0.0f;

    if (blockIdx.x < 3) {              // weight transpose for layer l = blockIdx.x
        __shared__ u16 tbuf[Hh * 136];
        int l = blockIdx.x;
        const float* W = W3 + l * Hh * Hh;
        u16* WT = WT3 + l * Hh * Hh;
        int tid = threadIdx.x;
#pragma unroll
        for (int i = 0; i < 16; i++) {
            int v = tid + 256 * i;     // float4 idx over 4096
            int r = v >> 5, c4 = v & 31;
            float4 d = ((const float4*)W)[v];
            u16* p = tbuf + r * 136 + c4 * 4;
            p[0] = f2bf(d.x); p[1] = f2bf(d.y); p[2] = f2bf(d.z); p[3] = f2bf(d.w);
        }
        __syncthreads();
#pragma unroll
        for (int i = 0; i < 64; i++) {
            int o = tid + 256 * i;     // u16 idx over 16384
            int n = o >> 7, k = o & 127;
            WT[o] = tbuf[k * 136 + n];
        }
    }
}

// ---------------- in-degree histogram ----------------
__global__ void k_deg(const int* __restrict__ ei, int* __restrict__ indeg) {
    int e = blockIdx.x * blockDim.x + threadIdx.x;
    if (e < Ee) atomicAdd(&indeg[ei[Ee + e]], 1);
}

// ---------------- scan phase 1 + dis + gstart (fused) ----------------
__global__ __launch_bounds__(256) void k_scan1(const int* __restrict__ indeg,
                                               int* __restrict__ rs,
                                               int* __restrict__ bsum,
                                               float* __restrict__ dis,
                                               const int* __restrict__ batch,
                                               int* __restrict__ gstart) {
    __shared__ int ts[256];
    int b = blockIdx.x;
    int t = threadIdx.x;
    int base = b * SB + t * 4;
    int v[4] = {0, 0, 0, 0};
#pragma unroll
    for (int j = 0; j < 4; j++) {
        int i = base + j;
        if (i < Nn) { v[j] = indeg[i]; dis[i] = rsqrtf((float)v[j] + 1.0f); }
    }
    // graph bounds: global thread id < G+1 does a binary search
    int g = b * 256 + t;
    if (g <= Gg) {
        int lo = 0, hi = Nn;
        while (lo < hi) {
            int mid = (lo + hi) >> 1;
            if (batch[mid] < g) lo = mid + 1; else hi = mid;
        }
        gstart[g] = lo;
    }
    int tsum = v[0] + v[1] + v[2] + v[3];
    ts[t] = tsum;
    __syncthreads();
    for (int off = 1; off < 256; off <<= 1) {
        int x = (t >= off) ? ts[t - off] : 0;
        __syncthreads();
        ts[t] += x;
        __syncthreads();
    }
    int run = (t == 0) ? 0 : ts[t - 1];
    if (t == 255) bsum[b] = ts[255];
#pragma unroll
    for (int j = 0; j < 4; j++) {
        int i = base + j;
        if (i < Nn) { rs[i] = run; run += v[j]; }
    }
}

// ---------------- scan phase 2: per-block redundant top-scan + add ----------------
__global__ __launch_bounds__(256) void k_scan2(int* __restrict__ rs,
                                               const int* __restrict__ bsum) {
    __shared__ int lboff[NSB];
    int t = threadIdx.x;
    if (t < 64) {
        int orig = (t < NSB) ? bsum[t] : 0;
        int v = orig;
#pragma unroll
        for (int off = 1; off < 64; off <<= 1) {
            int u = __shfl_up(v, off, 64);
            if (t >= off) v += u;
        }
        if (t < NSB) lboff[t] = v - orig;   // exclusive
    }
    __syncthreads();
    int i = blockIdx.x * blockDim.x + t;
    if (i < Nn) rs[i] += lboff[i >> 10];
}

// ---------------- counting-sort fill: packed {src,weight}, NT stream store ----------------
// After this kernel rs[d] == end of segment d.
__global__ void k_fill(const int* __restrict__ ei, int* __restrict__ rs,
                       const float* __restrict__ dis, Edge* __restrict__ edges) {
    int e = blockIdx.x * blockDim.x + threadIdx.x;
    if (e >= Ee) return;
    int s = ei[e];
    int d = ei[Ee + e];
    int slot = atomicAdd(&rs[d], 1);
    float w = dis[s] * dis[d];
    u64 rec = ((u64)__float_as_uint(w) << 32) | (u32)s;   // {s low, w high} little-endian
    __builtin_nontemporal_store(rec, (u64*)&edges[slot]);
}

// ---------------- MFMA GEMM: Yh[N,H](bf16) = Xh[N,H](bf16) @ W ----------------
__global__ __launch_bounds__(256) void k_gemm(const u16* __restrict__ Xh,
                                              const u16* __restrict__ WT,
                                              u16* __restrict__ Yh) {
    __shared__ u16 wt[Hh * 136];
    int tid = threadIdx.x;
#pragma unroll
    for (int i = 0; i < 8; i++) {
        int v = tid + 256 * i;            // uint4 idx over 2048
        int n = v >> 4, k8 = v & 15;
        uint4 d = ((const uint4*)WT)[v];
        *((uint4*)(wt + n * 136 + k8 * 8)) = d;
    }
    __syncthreads();

    int wv = tid >> 6, lane = tid & 63;
    int m = lane & 15, q = lane >> 4;
    int row0 = blockIdx.x * 64 + wv * 16;
    int lrow = row0 + m;
    if (lrow >= Nn) lrow = Nn - 1;        // clamp load row; stores guarded
    const u16* xrow = Xh + lrow * Hh + q * 8;

    f32x4 acc[8] = {};
#pragma unroll
    for (int k0 = 0; k0 < Hh; k0 += 32) {
        bf16x8 a = *(const bf16x8*)(xrow + k0);
#pragma unroll
        for (int t = 0; t < 8; t++) {
            bf16x8 b = *(const bf16x8*)(wt + (t * 16 + m) * 136 + k0 + q * 8);
            acc[t] = __builtin_amdgcn_mfma_f32_16x16x32_bf16(a, b, acc[t], 0, 0, 0);
        }
    }

    int orow0 = row0 + q * 4;
#pragma unroll
    for (int t = 0; t < 8; t++) {
#pragma unroll
        for (int r = 0; r < 4; r++) {
            int rr = orow0 + r;
            if (rr < Nn) Yh[rr * Hh + t * 16 + m] = f2bf(acc[t][r]);
        }
    }
}

// ---------------- CSR gather: bf16 rows, packed edges, unroll 8, fp32 accumulate ----------------
__global__ __launch_bounds__(256) void k_gather(const u16* __restrict__ Hb,
                                                const float* __restrict__ dis,
                                                const float* __restrict__ bias,
                                                const int* __restrict__ rs,
                                                const Edge* __restrict__ edges,
                                                float* __restrict__ A) {
    int node = blockIdx.x * 4 + (threadIdx.x >> 6);
    if (node >= Nn) return;
    int lane = threadIdx.x & 63;

    float dn = dis[node];
    u32 hv = ((const u32*)(Hb + node * Hh))[lane];
    float2 bv = ((const float2*)bias)[lane];
    float sn = dn * dn;
    float2 acc;
    acc.x = bf_lo(hv) * sn + bv.x;
    acc.y = bf_hi(hv) * sn + bv.y;

    int beg = (node == 0) ? 0 : rs[node - 1];
    int end = rs[node];

    int j = beg;
    for (; j + 7 < end; j += 8) {
        Edge e0 = edges[j],     e1 = edges[j + 1];
        Edge e2 = edges[j + 2], e3 = edges[j + 3];
        Edge e4 = edges[j + 4], e5 = edges[j + 5];
        Edge e6 = edges[j + 6], e7 = edges[j + 7];
        u32 v0 = ((const u32*)(Hb + e0.s * Hh))[lane];
        u32 v1 = ((const u32*)(Hb + e1.s * Hh))[lane];
        u32 v2 = ((const u32*)(Hb + e2.s * Hh))[lane];
        u32 v3 = ((const u32*)(Hb + e3.s * Hh))[lane];
        u32 v4 = ((const u32*)(Hb + e4.s * Hh))[lane];
        u32 v5 = ((const u32*)(Hb + e5.s * Hh))[lane];
        u32 v6 = ((const u32*)(Hb + e6.s * Hh))[lane];
        u32 v7 = ((const u32*)(Hb + e7.s * Hh))[lane];
        acc.x += bf_lo(v0) * e0.w + bf_lo(v1) * e1.w + bf_lo(v2) * e2.w + bf_lo(v3) * e3.w
               + bf_lo(v4) * e4.w + bf_lo(v5) * e5.w + bf_lo(v6) * e6.w + bf_lo(v7) * e7.w;
        acc.y += bf_hi(v0) * e0.w + bf_hi(v1) * e1.w + bf_hi(v2) * e2.w + bf_hi(v3) * e3.w
               + bf_hi(v4) * e4.w + bf_hi(v5) * e5.w + bf_hi(v6) * e6.w + bf_hi(v7) * e7.w;
    }
    for (; j < end; j++) {
        Edge e0 = edges[j];
        u32 v0 = ((const u32*)(Hb + e0.s * Hh))[lane];
        acc.x += bf_lo(v0) * e0.w;
        acc.y += bf_hi(v0) * e0.w;
    }
    ((float2*)(A + node * Hh))[lane] = acc;
}

// ---------------- BN stats: per-channel sum & sumsq ----------------
__global__ __launch_bounds__(256) void k_stats(const float* __restrict__ A,
                                               float* __restrict__ stats) {
    __shared__ float s1[256], s2[256];
    int tid = threadIdx.x;
    int c = tid & 127;
    int half = tid >> 7;
    float sum = 0.f, sq = 0.f;
    for (int r = blockIdx.x * 2 + half; r < Nn; r += gridDim.x * 2) {
        float v = A[r * Hh + c];
        sum += v;
        sq += v * v;
    }
    s1[tid] = sum;
    s2[tid] = sq;
    __syncthreads();
    if (half == 0) {
        atomicAdd(&stats[c], s1[c] + s1[c + 128]);
        atomicAdd(&stats[Hh + c], s2[c] + s2[c + 128]);
    }
}

// ---------------- BN normalize + affine + relu; emit bf16 (next gemm) and/or fp32 ----------------
__global__ void k_norm(const float* __restrict__ A, const float* __restrict__ stats,
                       const float* __restrict__ gam, const float* __restrict__ bet,
                       float* __restrict__ Xo, u16* __restrict__ Xh, int wf32) {
    int tid = blockIdx.x * blockDim.x + threadIdx.x;
    if (tid >= Nn * 32) return;
    int c4 = tid & 31;
    float4 v = ((const float4*)A)[tid];
    float4 o;
#pragma unroll
    for (int j = 0; j < 4; j++) {
        int c = c4 * 4 + j;
        float mu = stats[c] * (1.0f / Nn);
        float var = stats[Hh + c] * (1.0f / Nn) - mu * mu;
        float istd = rsqrtf(var + EPSf);
        float val = ((&v.x)[j] - mu) * istd * gam[c] + bet[c];
        (&o.x)[j] = fmaxf(val, 0.0f);
    }
    if (wf32) ((float4*)Xo)[tid] = o;
    if (Xh) {
        ushort4 h;
        h.x = f2bf(o.x); h.y = f2bf(o.y); h.z = f2bf(o.z); h.w = f2bf(o.w);
        ((ushort4*)Xh)[tid] = h;
    }
}

// ---------------- fused segmented mean pool + MLP head: one block per graph ----------------
__global__ __launch_bounds__(128) void k_poolmlp(const float* __restrict__ X,
                                                 const int* __restrict__ gstart,
                                                 const float* __restrict__ W1,
                                                 const float* __restrict__ b1,
                                                 const float* __restrict__ W2,
                                                 const float* __restrict__ b2,
                                                 float* __restrict__ out) {
    int g = blockIdx.x;
    int c = threadIdx.x;
    __shared__ float p[Hh];
    __shared__ float hid[Hh];
    int s = gstart[g], e = gstart[g + 1];
    float sum = 0.0f;
    for (int r = s; r < e; r++) sum += X[r * Hh + c];
    int n = e - s;
    p[c] = sum / (float)(n > 1 ? n : 1);
    __syncthreads();
    float acc = b1[c];
    for (int k = 0; k < Hh; k++) acc += p[k] * W1[k * Hh + c];
    hid[c] = fmaxf(acc, 0.0f);
    __syncthreads();
    if (c < Cc) {
        float acc2 = b2[c];
        for (int k = 0; k < Hh; k++) acc2 += hid[k] * W2[k * Cc + c];
        out[g * Cc + c] = acc2;
    }
}

extern "C" void kernel_launch(void* const* d_in, const int* in_sizes, int n_in,
                              void* d_out, int out_size, void* d_ws, size_t ws_size,
                              hipStream_t stream) {
    const float* x      = (const float*)d_in[0];
    const int*   ei     = (const int*)d_in[1];
    const int*   batch  = (const int*)d_in[2];
    const float* conv_w = (const float*)d_in[3];
    const float* conv_b = (const float*)d_in[4];
    const float* bn_g   = (const float*)d_in[5];
    const float* bn_b   = (const float*)d_in[6];
    const float* w1     = (const float*)d_in[7];
    const float* b1     = (const float*)d_in[8];
    const float* w2     = (const float*)d_in[9];
    const float* b2     = (const float*)d_in[10];
    float* out = (float*)d_out;

    float* B1      = (float*)d_ws;              // N*H fp32 (agg; final normalized x)
    u16*   Xh      = (u16*)(B1 + Nn * Hh);      // N*H bf16 (gemm input)
    u16*   Yh      = Xh + Nn * Hh;              // N*H bf16 (gemm out, gather src)
    u16*   WT      = Yh + Nn * Hh;              // 3*H*H bf16 (W^T)
    float* dis     = (float*)(WT + 3 * Hh * Hh);// N
    float* stats3  = dis + Nn;                  // 3*2*H
    int*   indeg   = (int*)(stats3 + 3 * 2 * Hh); // N
    int*   rs      = indeg + Nn;                // N
    int*   gstart  = rs + Nn;                   // G+1
    int*   bsum    = gstart + Gg + 1;           // NSB
    uintptr_t ep   = (uintptr_t)(bsum + NSB);
    Edge*  edges   = (Edge*)((ep + 7) & ~(uintptr_t)7);   // E packed records

    // ---- fused prologue + CSR build ----
    k_pre<<<(Nn * 32 + 255) / 256, 256, 0, stream>>>(x, Xh, conv_w, WT, indeg, stats3);
    k_deg<<<(Ee + 255) / 256, 256, 0, stream>>>(ei, indeg);
    k_scan1<<<NSB, 256, 0, stream>>>(indeg, rs, bsum, dis, batch, gstart);
    k_scan2<<<(Nn + 255) / 256, 256, 0, stream>>>(rs, bsum);
    k_fill<<<(Ee + 255) / 256, 256, 0, stream>>>(ei, rs, dis, edges);

    for (int l = 0; l < 3; l++) {
        float* stats = stats3 + l * 2 * Hh;
        k_gemm<<<(Nn + 63) / 64, 256, 0, stream>>>(Xh, WT + l * Hh * Hh, Yh);
        k_gather<<<(Nn + 3) / 4, 256, 0, stream>>>(Yh, dis, conv_b + l * Hh, rs,
                                                   edges, B1);
        k_stats<<<256, 256, 0, stream>>>(B1, stats);
        k_norm<<<(Nn * 32 + 255) / 256, 256, 0, stream>>>(
            B1, stats, bn_g + l * Hh, bn_b + l * Hh,
            B1, (l < 2) ? Xh : (u16*)nullptr, (l == 2) ? 1 : 0);
    }

    k_poolmlp<<<Gg, 128, 0, stream>>>(B1, gstart, w1, b1, w2, b2, out);
}